// Round 3
// baseline (10002.356 us; speedup 1.0000x reference)
//
#include <hip/hip_runtime.h>
#include <math.h>

// ---------------------------------------------------------------------------
// GPNN cell, fp32, workspace-adaptive batch chunking.
#define DMODEL 768
#define NHEADS 12
#define HEADD  64
#define NLAYERS 2
#define FFD    3072
#define BATCH  64
#define FRAMES 16
#define NOBJ   9
#define TWO_N  (2*NOBJ)                 // 18
#define ROWS_PER_B (TWO_N*FRAMES)       // 288 token rows per batch
#define NBF    (BATCH*FRAMES)           // 1024
//
// Token row order: r = (b*2N + n2)*F + f  (transformer layout), so
// tmp_edge[b,f,n2,:] == X row r with no transpose.
//
// Per-chunk ws layout (floats), R = 288*CB rows:
//   Qc (R*2304) | Xc (R*768) | Yc (R*768) | Zc (R*768) | EWHc (CB*16*768) | WEc (R)
// ---------------------------------------------------------------------------

__device__ __forceinline__ float gelu_f(float x) {
    return 0.5f * x * (1.0f + erff(x * 0.70710678118654752440f));
}

// ---------------- GEMM: C = [acc? C : 0] + act(A @ W + bias) ----------------
// A: M x K (lda), W: K x N (ldw), C: M x N (ldc). M%64==0, N%64==0, K%16==0.
#define BM 64
#define BN 64
#define BKk 16
#define LDP 68

__global__ __launch_bounds__(256) void gemm_f32(
    const float* __restrict__ A, int lda,
    const float* __restrict__ W, int ldw,
    const float* __restrict__ bias,
    float* __restrict__ C, int ldc,
    int M, int K, int N, int act, int acc)
{
    __shared__ float As[BKk][LDP];   // [k][m]
    __shared__ float Bs[BKk][LDP];   // [k][n]
    const int tid = threadIdx.x;
    const int nTiles = N / BN;
    const int col0 = (blockIdx.x % nTiles) * BN;
    const int row0 = (blockIdx.x / nTiles) * BM;
    const int tm = tid >> 4, tn = tid & 15;
    const int arow = tid >> 2;          // 0..63
    const int akv  = (tid & 3) << 2;    // 0,4,8,12
    const int brow = tid >> 4;          // 0..15
    const int bcol = (tid & 15) << 2;   // 0..60

    float accv[4][4];
    #pragma unroll
    for (int i = 0; i < 4; i++)
        #pragma unroll
        for (int j = 0; j < 4; j++) accv[i][j] = 0.f;

    const float* Ap = A + (size_t)(row0 + arow) * lda + akv;
    const float* Wp = W + (size_t)brow * ldw + col0 + bcol;

    for (int k0 = 0; k0 < K; k0 += BKk) {
        float4 av = *(const float4*)(Ap + k0);
        float4 bv = *(const float4*)(Wp + (size_t)k0 * ldw);
        __syncthreads();
        As[akv+0][arow] = av.x; As[akv+1][arow] = av.y;
        As[akv+2][arow] = av.z; As[akv+3][arow] = av.w;
        *(float4*)&Bs[brow][bcol] = bv;
        __syncthreads();
        #pragma unroll
        for (int k = 0; k < BKk; k++) {
            float4 a4 = *(const float4*)&As[k][tm << 2];
            float4 b4 = *(const float4*)&Bs[k][tn << 2];
            float ar[4] = {a4.x, a4.y, a4.z, a4.w};
            float br[4] = {b4.x, b4.y, b4.z, b4.w};
            #pragma unroll
            for (int i = 0; i < 4; i++)
                #pragma unroll
                for (int j = 0; j < 4; j++)
                    accv[i][j] = fmaf(ar[i], br[j], accv[i][j]);
        }
    }

    float bvals[4] = {0.f, 0.f, 0.f, 0.f};
    if (bias) {
        float4 b4 = *(const float4*)&bias[col0 + (tn << 2)];
        bvals[0] = b4.x; bvals[1] = b4.y; bvals[2] = b4.z; bvals[3] = b4.w;
    }
    #pragma unroll
    for (int i = 0; i < 4; i++) {
        int row = row0 + (tm << 2) + i;
        float* cp = C + (size_t)row * ldc + col0 + (tn << 2);
        float v[4];
        #pragma unroll
        for (int j = 0; j < 4; j++) v[j] = accv[i][j] + bvals[j];
        if (act) {
            #pragma unroll
            for (int j = 0; j < 4; j++) v[j] = gelu_f(v[j]);
        }
        if (acc) {
            float4 p = *(const float4*)cp;
            v[0] += p.x; v[1] += p.y; v[2] += p.z; v[3] += p.w;
        }
        *(float4*)cp = make_float4(v[0], v[1], v[2], v[3]);
    }
}

// ---------------- row LayerNorm (+optional residual, +optional GELU) -------
__global__ __launch_bounds__(256) void ln_act_f32(
    const float* __restrict__ in, const float* __restrict__ res,
    const float* __restrict__ gamma, const float* __restrict__ beta,
    float* __restrict__ out, int do_gelu)
{
    const int row = blockIdx.x;
    const int tid = threadIdx.x;
    const size_t base = (size_t)row * DMODEL;
    float x0 = in[base + tid];
    float x1 = in[base + tid + 256];
    float x2 = in[base + tid + 512];
    if (res) {
        x0 += res[base + tid];
        x1 += res[base + tid + 256];
        x2 += res[base + tid + 512];
    }
    float s  = x0 + x1 + x2;
    float ss = x0*x0 + x1*x1 + x2*x2;
    #pragma unroll
    for (int o = 32; o > 0; o >>= 1) {
        s  += __shfl_down(s,  o);
        ss += __shfl_down(ss, o);
    }
    __shared__ float sred[4], ssred[4], tot[2];
    const int lane = tid & 63, w = tid >> 6;
    if (lane == 0) { sred[w] = s; ssred[w] = ss; }
    __syncthreads();
    if (tid == 0) {
        tot[0] = sred[0] + sred[1] + sred[2] + sred[3];
        tot[1] = ssred[0] + ssred[1] + ssred[2] + ssred[3];
    }
    __syncthreads();
    const float mean = tot[0] * (1.0f / DMODEL);
    const float var  = tot[1] * (1.0f / DMODEL) - mean * mean;
    const float rstd = rsqrtf(var + 1e-5f);
    #pragma unroll
    for (int rep = 0; rep < 3; rep++) {
        int d = tid + rep * 256;
        float x = (rep == 0) ? x0 : (rep == 1) ? x1 : x2;
        float y = (x - mean) * rstd * gamma[d] + beta[d];
        if (do_gelu) y = gelu_f(y);
        out[base + d] = y;
    }
}

// ---------------- attention: one block per (local sequence, head), T=16 ----
__global__ __launch_bounds__(256) void attn_k(
    const float* __restrict__ QKV,   // local R x 2304
    float* __restrict__ O)           // local R x 768
{
    const int blk = blockIdx.x;
    const int h = blk % NHEADS;
    const int s = blk / NHEADS;
    __shared__ float q[16][HEADD], k[16][HEADD], v[16][HEADD], sc[16][17];
    const int tid = threadIdx.x;
    for (int idx = tid; idx < 16 * HEADD; idx += 256) {
        int t = idx >> 6, d = idx & 63;
        size_t base = (size_t)(s * 16 + t) * (3 * DMODEL) + h * HEADD + d;
        q[t][d] = QKV[base];
        k[t][d] = QKV[base + DMODEL];
        v[t][d] = QKV[base + 2 * DMODEL];
    }
    __syncthreads();
    {
        int qt = tid >> 4, kt = tid & 15;
        float a = 0.f;
        #pragma unroll
        for (int d = 0; d < HEADD; d++) a += q[qt][d] * k[kt][d];
        sc[qt][kt] = a * 0.125f;
    }
    __syncthreads();
    if (tid < 16) {
        float m = -1e30f;
        #pragma unroll
        for (int j = 0; j < 16; j++) m = fmaxf(m, sc[tid][j]);
        float sum = 0.f;
        #pragma unroll
        for (int j = 0; j < 16; j++) { float e = expf(sc[tid][j] - m); sc[tid][j] = e; sum += e; }
        float inv = 1.0f / sum;
        #pragma unroll
        for (int j = 0; j < 16; j++) sc[tid][j] *= inv;
    }
    __syncthreads();
    for (int idx = tid; idx < 16 * HEADD; idx += 256) {
        int qt = idx >> 6, d = idx & 63;
        float a = 0.f;
        #pragma unroll
        for (int kt = 0; kt < 16; kt++) a += sc[qt][kt] * v[kt][d];
        O[(size_t)(s * 16 + qt) * DMODEL + h * HEADD + d] = a;
    }
}

// ---------------- gathers (chunk-local dst, global src via r0) -------------
__global__ __launch_bounds__(256) void gather_cat1_k(
    const float* __restrict__ hf, const float* __restrict__ obj,
    const float* __restrict__ edge, float* __restrict__ Q, int r0)
{
    const int rl = blockIdx.x;
    const int r = r0 + rl;
    const int f = r % FRAMES;
    const int sq = r / FRAMES;
    const int n2 = sq % TWO_N;
    const int b = sq / TWO_N;
    const int bf = b * FRAMES + f;
    const int n = (n2 < NOBJ) ? n2 : (n2 - NOBJ);
    const float4* hfp = (const float4*)(hf + (size_t)bf * DMODEL);
    const float4* edp = (const float4*)(edge + ((size_t)bf * NOBJ + n) * DMODEL);
    const float4* obp = (const float4*)(obj + ((size_t)bf * NOBJ + n) * DMODEL);
    const float4* s0 = (n2 < NOBJ) ? hfp : obp;
    const float4* s2 = (n2 < NOBJ) ? obp : hfp;
    float4* dst = (float4*)(Q + (size_t)rl * (3 * DMODEL));
    const int Q4 = DMODEL / 4;
    for (int i = threadIdx.x; i < 3 * Q4; i += 256) {
        float4 vv = (i < Q4) ? s0[i] : (i < 2 * Q4 ? edp[i - Q4] : s2[i - 2 * Q4]);
        dst[i] = vv;
    }
}

__global__ __launch_bounds__(256) void gather_cat2_k(
    const float* __restrict__ hf, const float* __restrict__ obj,
    const float* __restrict__ X, float* __restrict__ Q, int r0)
{
    const int rl = blockIdx.x;
    const int r = r0 + rl;
    const int f = r % FRAMES;
    const int sq = r / FRAMES;
    const int n2 = sq % TWO_N;
    const int b = sq / TWO_N;
    const int bf = b * FRAMES + f;
    const float4* s0 = (n2 < NOBJ)
        ? (const float4*)(hf + (size_t)bf * DMODEL)
        : (const float4*)(obj + ((size_t)bf * NOBJ + (n2 - NOBJ)) * DMODEL);
    const float4* s1 = (const float4*)(X + (size_t)rl * DMODEL);
    float4* dst = (float4*)(Q + (size_t)rl * (2 * DMODEL));
    const int Q4 = DMODEL / 4;
    for (int i = threadIdx.x; i < 2 * Q4; i += 256) {
        dst[i] = (i < Q4) ? s0[i] : s1[i - Q4];
    }
}

// ---------------- weight_edge = sigmoid(X . W_l + b_l), one wave per row ----
__global__ __launch_bounds__(256) void wedge_k(
    const float* __restrict__ X, const float* __restrict__ Wl,
    const float* __restrict__ bl, float* __restrict__ WE)
{
    const int row = blockIdx.x * 4 + (threadIdx.x >> 6);
    const int lane = threadIdx.x & 63;
    const float* xp = X + (size_t)row * DMODEL;
    float a = 0.f;
    #pragma unroll
    for (int i = 0; i < DMODEL / 64; i++)
        a += xp[lane + i * 64] * Wl[lane + i * 64];
    #pragma unroll
    for (int o = 32; o > 0; o >>= 1) a += __shfl_down(a, o);
    if (lane == 0) WE[row] = 1.0f / (1.0f + expf(-(a + bl[0])));
}

// ---------------- ewh[bf_local,:] = sum_{n2<N} WE[rl] * m_v[rl,:] -----------
__global__ __launch_bounds__(256) void ewh_k(
    const float* __restrict__ MV, const float* __restrict__ WE,
    float* __restrict__ EWH)
{
    const int bfl = blockIdx.x;
    const int bl = bfl / FRAMES, f = bfl % FRAMES;
    const int tid = threadIdx.x;
    #pragma unroll
    for (int rep = 0; rep < 3; rep++) {
        int d = tid + rep * 256;
        float acc = 0.f;
        #pragma unroll
        for (int n2 = 0; n2 < NOBJ; n2++) {
            int rl = (bl * TWO_N + n2) * FRAMES + f;
            acc += WE[rl] * MV[(size_t)rl * DMODEL + d];
        }
        EWH[(size_t)bfl * DMODEL + d] = acc;
    }
}

// ---------------- A rows for final GEMMs: msg_norm(x, msg, s) + x -----------
// local rows [0, CB*16): human; [CB*16, CB*160): obj.
__global__ __launch_bounds__(256) void buildA_k(
    const float* __restrict__ EWH, const float* __restrict__ MV,
    const float* __restrict__ WE,  const float* __restrict__ hf,
    const float* __restrict__ obj, const float* __restrict__ scale_h,
    const float* __restrict__ scale_o, float* __restrict__ Amat,
    int bf0, int nhuman)
{
    const int row = blockIdx.x;
    const int tid = threadIdx.x;
    const float* msgp; const float* xp; float wsc, sc;
    if (row < nhuman) {
        msgp = EWH + (size_t)row * DMODEL;
        xp   = hf  + (size_t)(bf0 + row) * DMODEL;
        wsc = 1.0f; sc = scale_h[0];
    } else {
        int idx = row - nhuman;
        int n   = idx % NOBJ;
        int bfl = idx / NOBJ;
        int bl = bfl / FRAMES, f = bfl % FRAMES;
        int rl = (bl * TWO_N + NOBJ + n) * FRAMES + f;
        msgp = MV + (size_t)rl * DMODEL;
        xp   = obj + ((size_t)(bf0 + bfl) * NOBJ + n) * DMODEL;
        wsc = WE[rl]; sc = scale_o[0];
    }
    float m0 = msgp[tid]       * wsc;
    float m1 = msgp[tid + 256] * wsc;
    float m2 = msgp[tid + 512] * wsc;
    float x0 = xp[tid], x1 = xp[tid + 256], x2 = xp[tid + 512];
    float sm = m0*m0 + m1*m1 + m2*m2;
    float sx = x0*x0 + x1*x1 + x2*x2;
    #pragma unroll
    for (int o = 32; o > 0; o >>= 1) {
        sm += __shfl_down(sm, o);
        sx += __shfl_down(sx, o);
    }
    __shared__ float smr[4], sxr[4], tot[2];
    const int lane = tid & 63, w = tid >> 6;
    if (lane == 0) { smr[w] = sm; sxr[w] = sx; }
    __syncthreads();
    if (tid == 0) {
        tot[0] = smr[0] + smr[1] + smr[2] + smr[3];
        tot[1] = sxr[0] + sxr[1] + sxr[2] + sxr[3];
    }
    __syncthreads();
    const float nm  = fmaxf(sqrtf(tot[0]), 1e-12f);
    const float fac = sqrtf(tot[1]) * sc / nm;
    const size_t ob = (size_t)row * DMODEL;
    Amat[ob + tid]       = m0 * fac + x0;
    Amat[ob + tid + 256] = m1 * fac + x1;
    Amat[ob + tid + 512] = m2 * fac + x2;
}

// ---------------------------------------------------------------------------
static inline void launch_gemm(const float* A, int lda, const float* W, int ldw,
                               const float* bias, float* C, int ldc,
                               int M, int K, int N, int act, int acc,
                               hipStream_t st)
{
    dim3 grid((N / BN) * (M / BM));
    gemm_f32<<<grid, 256, 0, st>>>(A, lda, W, ldw, bias, C, ldc, M, K, N, act, acc);
}

extern "C" void kernel_launch(void* const* d_in, const int* in_sizes, int n_in,
                              void* d_out, int out_size, void* d_ws, size_t ws_size,
                              hipStream_t stream)
{
    const float* hf   = (const float*)d_in[0];
    const float* obj  = (const float*)d_in[1];
    const float* edge = (const float*)d_in[2];
    const float* W_e1 = (const float*)d_in[3];
    const float* b_e1 = (const float*)d_in[4];
    const float* W_e2 = (const float*)d_in[5];
    const float* b_e2 = (const float*)d_in[6];
    const float* g_e  = (const float*)d_in[7];
    const float* be_e = (const float*)d_in[8];
    const float* W_m  = (const float*)d_in[9];
    const float* b_m  = (const float*)d_in[10];
    const float* W_mg = (const float*)d_in[11];
    const float* b_mg = (const float*)d_in[12];
    const float* g_mg = (const float*)d_in[13];
    const float* bb_mg= (const float*)d_in[14];
    const float* W_l  = (const float*)d_in[15];
    const float* b_l  = (const float*)d_in[16];
    const float* scale_h = (const float*)d_in[17];
    const float* scale_o = (const float*)d_in[18];
    const float* W_nh = (const float*)d_in[19];
    const float* b_nh = (const float*)d_in[20];
    const float* g_nh = (const float*)d_in[21];
    const float* bb_nh= (const float*)d_in[22];
    const float* W_no = (const float*)d_in[23];
    const float* b_no = (const float*)d_in[24];
    const float* g_no = (const float*)d_in[25];
    const float* bb_no= (const float*)d_in[26];
    const float* Wqkv = (const float*)d_in[27];
    const float* bqkv = (const float*)d_in[28];
    const float* Wo_t = (const float*)d_in[29];
    const float* bo_t = (const float*)d_in[30];
    const float* g1   = (const float*)d_in[31];
    const float* bb1  = (const float*)d_in[32];
    const float* Wf1  = (const float*)d_in[33];
    const float* bf1  = (const float*)d_in[34];
    const float* Wf2  = (const float*)d_in[35];
    const float* bf2  = (const float*)d_in[36];
    const float* g2   = (const float*)d_in[37];
    const float* bb2  = (const float*)d_in[38];

    float* out = (float*)d_out;
    float* ws  = (float*)d_ws;

    // Choose largest batch-chunk CB fitting ws_size.
    int CB = 4;
    {
        const int cands[5] = {64, 32, 16, 8, 4};
        for (int i = 0; i < 5; i++) {
            size_t R = (size_t)cands[i] * ROWS_PER_B;
            size_t need = (R * 4608 + (size_t)cands[i] * 16 * DMODEL + R + 4096)
                          * sizeof(float);
            if (need <= ws_size) { CB = cands[i]; break; }
        }
    }
    const int R = CB * ROWS_PER_B;          // rows per chunk
    const int nhuman = CB * FRAMES;         // human rows per chunk
    const int nobjr  = CB * FRAMES * NOBJ;  // obj rows per chunk

    float* Qc  = ws;                                 // R x 2304
    float* Xc  = Qc + (size_t)R * 2304;              // R x 768
    float* Yc  = Xc + (size_t)R * DMODEL;            // R x 768
    float* Zc  = Yc + (size_t)R * DMODEL;            // R x 768
    float* EWHc= Zc + (size_t)R * DMODEL;            // nhuman x 768
    float* WEc = EWHc + (size_t)nhuman * DMODEL;     // R

    for (int b0 = 0; b0 < BATCH; b0 += CB) {
        const int r0  = b0 * ROWS_PER_B;
        const int bf0 = b0 * FRAMES;

        // ---- edge MLP ----
        gather_cat1_k<<<R, 256, 0, stream>>>(hf, obj, edge, Qc, r0);
        launch_gemm(Qc, 3*DMODEL, W_e1, DMODEL, b_e1, Yc, DMODEL,
                    R, 3*DMODEL, DMODEL, 1, 0, stream);
        launch_gemm(Yc, DMODEL, W_e2, DMODEL, b_e2, Zc, DMODEL,
                    R, DMODEL, DMODEL, 0, 0, stream);
        ln_act_f32<<<R, 256, 0, stream>>>(Zc, nullptr, g_e, be_e, Xc, 1);

        // ---- transformer (2 layers) ----
        for (int l = 0; l < NLAYERS; l++) {
            launch_gemm(Xc, DMODEL, Wqkv + (size_t)l * DMODEL * 3 * DMODEL, 3*DMODEL,
                        bqkv + (size_t)l * 3 * DMODEL, Qc, 3*DMODEL,
                        R, DMODEL, 3*DMODEL, 0, 0, stream);
            attn_k<<<(R / 16) * NHEADS, 256, 0, stream>>>(Qc, Yc);
            launch_gemm(Yc, DMODEL, Wo_t + (size_t)l * DMODEL * DMODEL, DMODEL,
                        bo_t + (size_t)l * DMODEL, Zc, DMODEL,
                        R, DMODEL, DMODEL, 0, 0, stream);
            ln_act_f32<<<R, 256, 0, stream>>>(Zc, Xc, g1 + l*DMODEL, bb1 + l*DMODEL, Xc, 0);
            for (int c = 0; c < 4; c++) {
                launch_gemm(Xc, DMODEL, Wf1 + (size_t)l * DMODEL * FFD + c * DMODEL, FFD,
                            bf1 + (size_t)l * FFD + c * DMODEL, Yc, DMODEL,
                            R, DMODEL, DMODEL, 1, 0, stream);
                launch_gemm(Yc, DMODEL,
                            Wf2 + (size_t)l * FFD * DMODEL + (size_t)c * DMODEL * DMODEL, DMODEL,
                            (c == 0 ? bf2 + (size_t)l * DMODEL : nullptr), Zc, DMODEL,
                            R, DMODEL, DMODEL, 0, (c > 0) ? 1 : 0, stream);
            }
            ln_act_f32<<<R, 256, 0, stream>>>(Zc, Xc, g2 + l*DMODEL, bb2 + l*DMODEL, Xc, 0);
        }

        // ---- message passing epilogue (chunk-local) ----
        wedge_k<<<R / 4, 256, 0, stream>>>(Xc, W_l, b_l, WEc);
        gather_cat2_k<<<R, 256, 0, stream>>>(hf, obj, Xc, Qc, r0);
        launch_gemm(Qc, 2*DMODEL, W_m, DMODEL, b_m, Yc, DMODEL,
                    R, 2*DMODEL, DMODEL, 1, 0, stream);
        launch_gemm(Yc, DMODEL, W_mg, DMODEL, b_mg, Zc, DMODEL,
                    R, DMODEL, DMODEL, 0, 0, stream);
        ln_act_f32<<<R, 256, 0, stream>>>(Zc, nullptr, g_mg, bb_mg, Yc, 1); // m_v -> Yc
        ewh_k<<<nhuman, 256, 0, stream>>>(Yc, WEc, EWHc);
        buildA_k<<<nhuman + nobjr, 256, 0, stream>>>(EWHc, Yc, WEc, hf, obj,
                                                     scale_h, scale_o, Zc, bf0, nhuman);
        // final projections into Qc, then LN+GELU straight to d_out slices
        launch_gemm(Zc, DMODEL, W_nh, DMODEL, b_nh, Qc, DMODEL,
                    nhuman, DMODEL, DMODEL, 0, 0, stream);
        launch_gemm(Zc + (size_t)nhuman * DMODEL, DMODEL, W_no, DMODEL, b_no,
                    Qc + (size_t)nhuman * DMODEL, DMODEL,
                    nobjr, DMODEL, DMODEL, 0, 0, stream);
        ln_act_f32<<<nhuman, 256, 0, stream>>>(Qc, nullptr, g_nh, bb_nh,
                                               out + (size_t)bf0 * DMODEL, 1);
        ln_act_f32<<<nobjr, 256, 0, stream>>>(Qc + (size_t)nhuman * DMODEL, nullptr,
                                              g_no, bb_no,
                                              out + (size_t)NBF * DMODEL
                                                  + (size_t)bf0 * NOBJ * DMODEL, 1);
    }
}

// Round 5
// 6716.131 us; speedup vs baseline: 1.4893x; 1.4893x over previous
//
#include <hip/hip_runtime.h>
#include <math.h>

// ---------------------------------------------------------------------------
// GPNN cell: split-bf16 (hi+lo) MFMA GEMMs, fp32 elsewhere.
#define DMODEL 768
#define NHEADS 12
#define HEADD  64
#define NLAYERS 2
#define FFD    3072
#define BATCH  64
#define FRAMES 16
#define NOBJ   9
#define TWO_N  (2*NOBJ)                 // 18
#define ROWS_PER_B (TWO_N*FRAMES)       // 288 rows per batch (mult of 128 when *CB)
#define NBF    (BATCH*FRAMES)           // 1024

typedef float f32x4 __attribute__((ext_vector_type(4)));
typedef short s16x8 __attribute__((ext_vector_type(8)));
typedef unsigned short u16x8 __attribute__((ext_vector_type(8)));

__device__ __forceinline__ float gelu_f(float x) {
    return 0.5f * x * (1.0f + erff(x * 0.70710678118654752440f));
}
__device__ __forceinline__ unsigned short f2bf(float x) {
    unsigned u = __float_as_uint(x);
    unsigned r = (u + 0x7fffu + ((u >> 16) & 1u)) >> 16;
    return (unsigned short)r;
}
__device__ __forceinline__ float bf2f(unsigned short h) {
    return __uint_as_float(((unsigned)h) << 16);
}
__device__ __forceinline__ void store_hl(float v, unsigned short* ph, unsigned short* pl) {
    unsigned short h = f2bf(v);
    *ph = h;
    *pl = f2bf(v - bf2f(h));
}

// ---------------- weight transpose + hi/lo convert:  W[K][N] -> T[N][K] ----
__global__ __launch_bounds__(256) void wconv_t(
    const float* __restrict__ W, unsigned short* __restrict__ Th,
    unsigned short* __restrict__ Tl, int K, int N)
{
    __shared__ float s[64][65];
    const int k0 = blockIdx.x * 64, n0 = blockIdx.y * 64;
    const int tid = threadIdx.x;
    for (int i = tid; i < 4096; i += 256) {
        int r = i >> 6, c = i & 63;
        s[r][c] = W[(size_t)(k0 + r) * N + n0 + c];
    }
    __syncthreads();
    for (int i = tid; i < 4096; i += 256) {
        int n = i >> 6, k = i & 63;
        float x = s[k][n];
        unsigned short h = f2bf(x);
        size_t o = (size_t)(n0 + n) * K + k0 + k;
        Th[o] = h;
        Tl[o] = f2bf(x - bf2f(h));
    }
}

// ---------------- split-bf16 MFMA GEMM -------------------------------------
// C[M][N] = [accum? C:0] + act(A @ B^T-style + bias), A rows K elems (hi/lo
// planes), B is WT[N][K] hi/lo planes (row stride ldb). Tile 128x128, 4 waves,
// K-step 32. A buffer must be padded to ceil(M,128) rows (garbage ok).
__global__ __launch_bounds__(256) void gemm_bf16s(
    const unsigned short* __restrict__ Ah, const unsigned short* __restrict__ Al,
    const unsigned short* __restrict__ Bh, const unsigned short* __restrict__ Bl,
    int ldb, int K,
    const float* __restrict__ bias,
    float* __restrict__ Cf, unsigned short* __restrict__ Chi,
    unsigned short* __restrict__ Clo,
    int ldc, int M, int act, int accum)
{
    __shared__ unsigned short lds[4 * 128 * 32];   // 32 KB: Ah|Al|Bh|Bl tiles
    const int tid = threadIdx.x;
    const int wid = tid >> 6, l = tid & 63;
    const int row0 = blockIdx.y * 128;
    const int col0 = blockIdx.x * 128;

    // staging: wave w stages plane w (128 rows x 32 elems, 8 iters x 16B/lane)
    const unsigned short* gb = (wid == 0) ? Ah : (wid == 1) ? Al : (wid == 2) ? Bh : Bl;
    const int ld = (wid < 2) ? K : ldb;
    const int rb = (wid < 2) ? row0 : col0;
    const unsigned short* gptr = gb + (size_t)(rb + (l >> 2)) * ld + (l & 3) * 8;
    int widx[8];
    #pragma unroll
    for (int j = 0; j < 8; j++) {
        int row = j * 16 + (l >> 2);
        widx[j] = wid * 4096 + row * 32 + (l & 3) * 8;
    }

    // fragment read offsets
    const int wr = wid >> 1, wc = wid & 1;
    const int fr = l & 15, fs = l >> 4;
    int aoff[4], boff[4];
    #pragma unroll
    for (int m = 0; m < 4; m++) aoff[m] = (wr * 64 + m * 16 + fr) * 32 + fs * 8;
    #pragma unroll
    for (int n = 0; n < 4; n++) boff[n] = (wc * 64 + n * 16 + fr) * 32 + fs * 8;

    f32x4 acc[4][4];
    #pragma unroll
    for (int m = 0; m < 4; m++)
        #pragma unroll
        for (int n = 0; n < 4; n++) acc[m][n] = (f32x4){0.f, 0.f, 0.f, 0.f};

    for (int k0 = 0; k0 < K; k0 += 32) {
        u16x8 r[8];
        #pragma unroll
        for (int j = 0; j < 8; j++)
            r[j] = *(const u16x8*)(gptr + (size_t)j * 16 * ld + k0);
        __syncthreads();
        #pragma unroll
        for (int j = 0; j < 8; j++)
            *(u16x8*)&lds[widx[j]] = r[j];
        __syncthreads();

        s16x8 ah[4], al[4], bh[4], bl[4];
        #pragma unroll
        for (int m = 0; m < 4; m++) {
            ah[m] = *(const s16x8*)&lds[aoff[m]];
            al[m] = *(const s16x8*)&lds[4096 + aoff[m]];
        }
        #pragma unroll
        for (int n = 0; n < 4; n++) {
            bh[n] = *(const s16x8*)&lds[8192 + boff[n]];
            bl[n] = *(const s16x8*)&lds[12288 + boff[n]];
        }
        #pragma unroll
        for (int m = 0; m < 4; m++)
            #pragma unroll
            for (int n = 0; n < 4; n++) {
                acc[m][n] = __builtin_amdgcn_mfma_f32_16x16x32_bf16(ah[m], bh[n], acc[m][n], 0, 0, 0);
                acc[m][n] = __builtin_amdgcn_mfma_f32_16x16x32_bf16(al[m], bh[n], acc[m][n], 0, 0, 0);
                acc[m][n] = __builtin_amdgcn_mfma_f32_16x16x32_bf16(ah[m], bl[n], acc[m][n], 0, 0, 0);
            }
    }

    // epilogue: C/D layout col = l&15, row = (l>>4)*4 + j  [m89-verified]
    #pragma unroll
    for (int n = 0; n < 4; n++) {
        int gcol = col0 + wc * 64 + n * 16 + fr;
        float bv = bias ? bias[gcol] : 0.f;
        #pragma unroll
        for (int m = 0; m < 4; m++) {
            int grow0 = row0 + wr * 64 + m * 16 + (fs << 2);
            #pragma unroll
            for (int j = 0; j < 4; j++) {
                int grow = grow0 + j;
                if (grow < M) {
                    float v = acc[m][n][j] + bv;
                    if (act) v = gelu_f(v);
                    size_t ci = (size_t)grow * ldc + gcol;
                    if (accum) v += Cf[ci];
                    if (Cf) Cf[ci] = v;
                    if (Chi) store_hl(v, &Chi[ci], &Clo[ci]);
                }
            }
        }
    }
}

// ---------------- row LayerNorm (+residual, +gelu), fp32 + optional planes --
__global__ __launch_bounds__(256) void ln_act_f32(
    const float* __restrict__ in, const float* __restrict__ res,
    const float* __restrict__ gamma, const float* __restrict__ beta,
    float* __restrict__ outf, unsigned short* __restrict__ outh,
    unsigned short* __restrict__ outl, int do_gelu)
{
    const int row = blockIdx.x;
    const int tid = threadIdx.x;
    const size_t base = (size_t)row * DMODEL;
    float x0 = in[base + tid];
    float x1 = in[base + tid + 256];
    float x2 = in[base + tid + 512];
    if (res) {
        x0 += res[base + tid];
        x1 += res[base + tid + 256];
        x2 += res[base + tid + 512];
    }
    float s  = x0 + x1 + x2;
    float ss = x0 * x0 + x1 * x1 + x2 * x2;
    #pragma unroll
    for (int o = 32; o > 0; o >>= 1) {
        s  += __shfl_down(s,  o);
        ss += __shfl_down(ss, o);
    }
    __shared__ float sred[4], ssred[4], tot[2];
    const int lane = tid & 63, w = tid >> 6;
    if (lane == 0) { sred[w] = s; ssred[w] = ss; }
    __syncthreads();
    if (tid == 0) {
        tot[0] = sred[0] + sred[1] + sred[2] + sred[3];
        tot[1] = ssred[0] + ssred[1] + ssred[2] + ssred[3];
    }
    __syncthreads();
    const float mean = tot[0] * (1.0f / DMODEL);
    const float var  = tot[1] * (1.0f / DMODEL) - mean * mean;
    const float rstd = rsqrtf(var + 1e-5f);
    #pragma unroll
    for (int rep = 0; rep < 3; rep++) {
        int d = tid + rep * 256;
        float x = (rep == 0) ? x0 : (rep == 1) ? x1 : x2;
        float y = (x - mean) * rstd * gamma[d] + beta[d];
        if (do_gelu) y = gelu_f(y);
        if (outf) outf[base + d] = y;
        if (outh) store_hl(y, &outh[base + d], &outl[base + d]);
    }
}

// ---------------- attention: one block per (local sequence, head), T=16 ----
__global__ __launch_bounds__(256) void attn_k(
    const float* __restrict__ QKV,   // local R x 2304
    unsigned short* __restrict__ Oh, unsigned short* __restrict__ Ol)
{
    const int blk = blockIdx.x;
    const int h = blk % NHEADS;
    const int s = blk / NHEADS;
    __shared__ float q[16][HEADD], k[16][HEADD], v[16][HEADD], sc[16][17];
    const int tid = threadIdx.x;
    for (int idx = tid; idx < 16 * HEADD; idx += 256) {
        int t = idx >> 6, d = idx & 63;
        size_t base = (size_t)(s * 16 + t) * (3 * DMODEL) + h * HEADD + d;
        q[t][d] = QKV[base];
        k[t][d] = QKV[base + DMODEL];
        v[t][d] = QKV[base + 2 * DMODEL];
    }
    __syncthreads();
    {
        int qt = tid >> 4, kt = tid & 15;
        float a = 0.f;
        #pragma unroll
        for (int d = 0; d < HEADD; d++) a += q[qt][d] * k[kt][d];
        sc[qt][kt] = a * 0.125f;
    }
    __syncthreads();
    if (tid < 16) {
        float m = -1e30f;
        #pragma unroll
        for (int j = 0; j < 16; j++) m = fmaxf(m, sc[tid][j]);
        float sum = 0.f;
        #pragma unroll
        for (int j = 0; j < 16; j++) { float e = expf(sc[tid][j] - m); sc[tid][j] = e; sum += e; }
        float inv = 1.0f / sum;
        #pragma unroll
        for (int j = 0; j < 16; j++) sc[tid][j] *= inv;
    }
    __syncthreads();
    for (int idx = tid; idx < 16 * HEADD; idx += 256) {
        int qt = idx >> 6, d = idx & 63;
        float a = 0.f;
        #pragma unroll
        for (int kt = 0; kt < 16; kt++) a += sc[qt][kt] * v[kt][d];
        size_t o = (size_t)(s * 16 + qt) * DMODEL + h * HEADD + d;
        store_hl(a, &Oh[o], &Ol[o]);
    }
}

// ---------------- gathers (write hi/lo planes) ------------------------------
__global__ __launch_bounds__(256) void gather_cat1_k(
    const float* __restrict__ hf, const float* __restrict__ obj,
    const float* __restrict__ edge, unsigned short* __restrict__ Qh,
    unsigned short* __restrict__ Ql, int r0)
{
    const int rl = blockIdx.x;
    const int r = r0 + rl;
    const int f = r % FRAMES;
    const int sq = r / FRAMES;
    const int n2 = sq % TWO_N;
    const int b = sq / TWO_N;
    const int bf = b * FRAMES + f;
    const int n = (n2 < NOBJ) ? n2 : (n2 - NOBJ);
    const float* hfp = hf + (size_t)bf * DMODEL;
    const float* edp = edge + ((size_t)bf * NOBJ + n) * DMODEL;
    const float* obp = obj + ((size_t)bf * NOBJ + n) * DMODEL;
    const float* s0 = (n2 < NOBJ) ? hfp : obp;
    const float* s2 = (n2 < NOBJ) ? obp : hfp;
    const size_t ob = (size_t)rl * (3 * DMODEL);
    for (int i = threadIdx.x; i < 3 * DMODEL; i += 256) {
        float v = (i < DMODEL) ? s0[i]
                : (i < 2 * DMODEL) ? edp[i - DMODEL] : s2[i - 2 * DMODEL];
        store_hl(v, &Qh[ob + i], &Ql[ob + i]);
    }
}

__global__ __launch_bounds__(256) void gather_cat2_k(
    const float* __restrict__ hf, const float* __restrict__ obj,
    const unsigned short* __restrict__ Xh, const unsigned short* __restrict__ Xl,
    unsigned short* __restrict__ Qh, unsigned short* __restrict__ Ql, int r0)
{
    const int rl = blockIdx.x;
    const int r = r0 + rl;
    const int f = r % FRAMES;
    const int sq = r / FRAMES;
    const int n2 = sq % TWO_N;
    const int b = sq / TWO_N;
    const int bf = b * FRAMES + f;
    const float* s0 = (n2 < NOBJ)
        ? hf + (size_t)bf * DMODEL
        : obj + ((size_t)bf * NOBJ + (n2 - NOBJ)) * DMODEL;
    const size_t ob = (size_t)rl * (2 * DMODEL);
    const size_t xb = (size_t)rl * DMODEL;
    for (int i = threadIdx.x; i < 2 * DMODEL; i += 256) {
        if (i < DMODEL) {
            store_hl(s0[i], &Qh[ob + i], &Ql[ob + i]);
        } else {
            Qh[ob + i] = Xh[xb + i - DMODEL];
            Ql[ob + i] = Xl[xb + i - DMODEL];
        }
    }
}

// ---------------- weight_edge = sigmoid(X . W_l + b_l) ----------------------
__global__ __launch_bounds__(256) void wedge_k(
    const float* __restrict__ X, const float* __restrict__ Wl,
    const float* __restrict__ bl, float* __restrict__ WE)
{
    const int row = blockIdx.x * 4 + (threadIdx.x >> 6);
    const int lane = threadIdx.x & 63;
    const float* xp = X + (size_t)row * DMODEL;
    float a = 0.f;
    #pragma unroll
    for (int i = 0; i < DMODEL / 64; i++)
        a += xp[lane + i * 64] * Wl[lane + i * 64];
    #pragma unroll
    for (int o = 32; o > 0; o >>= 1) a += __shfl_down(a, o);
    if (lane == 0) WE[row] = 1.0f / (1.0f + expf(-(a + bl[0])));
}

// ---------------- ewh[bf_local,:] = sum_{n2<N} WE[rl] * m_v[rl,:] -----------
__global__ __launch_bounds__(256) void ewh_k(
    const float* __restrict__ MV, const float* __restrict__ WE,
    float* __restrict__ EWH)
{
    const int bfl = blockIdx.x;
    const int bl = bfl / FRAMES, f = bfl % FRAMES;
    const int tid = threadIdx.x;
    #pragma unroll
    for (int rep = 0; rep < 3; rep++) {
        int d = tid + rep * 256;
        float acc = 0.f;
        #pragma unroll
        for (int n2 = 0; n2 < NOBJ; n2++) {
            int rl = (bl * TWO_N + n2) * FRAMES + f;
            acc += WE[rl] * MV[(size_t)rl * DMODEL + d];
        }
        EWH[(size_t)bfl * DMODEL + d] = acc;
    }
}

// ---------------- A rows for final GEMMs: msg_norm(x,msg,s)+x → hi/lo -------
__global__ __launch_bounds__(256) void buildA_k(
    const float* __restrict__ EWH, const float* __restrict__ MV,
    const float* __restrict__ WE,  const float* __restrict__ hf,
    const float* __restrict__ obj, const float* __restrict__ scale_h,
    const float* __restrict__ scale_o, unsigned short* __restrict__ Ahp,
    unsigned short* __restrict__ Alp, int bf0, int nhuman)
{
    const int row = blockIdx.x;
    const int tid = threadIdx.x;
    const float* msgp; const float* xp; float wsc, sc;
    if (row < nhuman) {
        msgp = EWH + (size_t)row * DMODEL;
        xp   = hf  + (size_t)(bf0 + row) * DMODEL;
        wsc = 1.0f; sc = scale_h[0];
    } else {
        int idx = row - nhuman;
        int n   = idx % NOBJ;
        int bfl = idx / NOBJ;
        int bl = bfl / FRAMES, f = bfl % FRAMES;
        int rl = (bl * TWO_N + NOBJ + n) * FRAMES + f;
        msgp = MV + (size_t)rl * DMODEL;
        xp   = obj + ((size_t)(bf0 + bfl) * NOBJ + n) * DMODEL;
        wsc = WE[rl]; sc = scale_o[0];
    }
    float m0 = msgp[tid]       * wsc;
    float m1 = msgp[tid + 256] * wsc;
    float m2 = msgp[tid + 512] * wsc;
    float x0 = xp[tid], x1 = xp[tid + 256], x2 = xp[tid + 512];
    float sm = m0*m0 + m1*m1 + m2*m2;
    float sx = x0*x0 + x1*x1 + x2*x2;
    #pragma unroll
    for (int o = 32; o > 0; o >>= 1) {
        sm += __shfl_down(sm, o);
        sx += __shfl_down(sx, o);
    }
    __shared__ float smr[4], sxr[4], tot[2];
    const int lane = tid & 63, w = tid >> 6;
    if (lane == 0) { smr[w] = sm; sxr[w] = sx; }
    __syncthreads();
    if (tid == 0) {
        tot[0] = smr[0] + smr[1] + smr[2] + smr[3];
        tot[1] = sxr[0] + sxr[1] + sxr[2] + sxr[3];
    }
    __syncthreads();
    const float nm  = fmaxf(sqrtf(tot[0]), 1e-12f);
    const float fac = sqrtf(tot[1]) * sc / nm;
    const size_t ob = (size_t)row * DMODEL;
    store_hl(m0 * fac + x0, &Ahp[ob + tid],       &Alp[ob + tid]);
    store_hl(m1 * fac + x1, &Ahp[ob + tid + 256], &Alp[ob + tid + 256]);
    store_hl(m2 * fac + x2, &Ahp[ob + tid + 512], &Alp[ob + tid + 512]);
}

// ---------------------------------------------------------------------------
extern "C" void kernel_launch(void* const* d_in, const int* in_sizes, int n_in,
                              void* d_out, int out_size, void* d_ws, size_t ws_size,
                              hipStream_t stream)
{
    const float* hf   = (const float*)d_in[0];
    const float* obj  = (const float*)d_in[1];
    const float* edge = (const float*)d_in[2];
    const float* W_e1 = (const float*)d_in[3];
    const float* b_e1 = (const float*)d_in[4];
    const float* W_e2 = (const float*)d_in[5];
    const float* b_e2 = (const float*)d_in[6];
    const float* g_e  = (const float*)d_in[7];
    const float* be_e = (const float*)d_in[8];
    const float* W_m  = (const float*)d_in[9];
    const float* b_m  = (const float*)d_in[10];
    const float* W_mg = (const float*)d_in[11];
    const float* b_mg = (const float*)d_in[12];
    const float* g_mg = (const float*)d_in[13];
    const float* bb_mg= (const float*)d_in[14];
    const float* W_l  = (const float*)d_in[15];
    const float* b_l  = (const float*)d_in[16];
    const float* scale_h = (const float*)d_in[17];
    const float* scale_o = (const float*)d_in[18];
    const float* W_nh = (const float*)d_in[19];
    const float* b_nh = (const float*)d_in[20];
    const float* g_nh = (const float*)d_in[21];
    const float* bb_nh= (const float*)d_in[22];
    const float* W_no = (const float*)d_in[23];
    const float* b_no = (const float*)d_in[24];
    const float* g_no = (const float*)d_in[25];
    const float* bb_no= (const float*)d_in[26];
    const float* Wqkv = (const float*)d_in[27];
    const float* bqkv = (const float*)d_in[28];
    const float* Wo_t = (const float*)d_in[29];
    const float* bo_t = (const float*)d_in[30];
    const float* g1   = (const float*)d_in[31];
    const float* bb1  = (const float*)d_in[32];
    const float* Wf1  = (const float*)d_in[33];
    const float* bf1  = (const float*)d_in[34];
    const float* Wf2  = (const float*)d_in[35];
    const float* bf2  = (const float*)d_in[36];
    const float* g2   = (const float*)d_in[37];
    const float* bb2  = (const float*)d_in[38];

    float* out = (float*)d_out;
    unsigned short* wts = (unsigned short*)d_ws;

    // ---- transposed hi/lo weight planes in ws (converted every launch) ----
    size_t wo = 0;
    auto alloc2 = [&](size_t n, unsigned short** h, unsigned short** l) {
        *h = wts + wo; *l = wts + wo + n; wo += 2 * n;
    };
    unsigned short *we1h,*we1l,*we2h,*we2l,*wmh,*wml,*wmgh,*wmgl,*wnhh,*wnhl,*wnoh,*wnol;
    unsigned short *qkvh[2],*qkvl[2],*woh[2],*wol[2],*wf1h[2],*wf1l[2],*wf2h[2],*wf2l[2];
    alloc2((size_t)768*2304, &we1h, &we1l);
    alloc2((size_t)768*768,  &we2h, &we2l);
    alloc2((size_t)768*1536, &wmh,  &wml);
    alloc2((size_t)768*768,  &wmgh, &wmgl);
    alloc2((size_t)768*768,  &wnhh, &wnhl);
    alloc2((size_t)768*768,  &wnoh, &wnol);
    for (int l = 0; l < 2; l++) {
        alloc2((size_t)2304*768, &qkvh[l], &qkvl[l]);
        alloc2((size_t)768*768,  &woh[l],  &wol[l]);
        alloc2((size_t)3072*768, &wf1h[l], &wf1l[l]);
        alloc2((size_t)768*3072, &wf2h[l], &wf2l[l]);
    }
    const size_t wbytes = wo * sizeof(unsigned short);

    wconv_t<<<dim3(2304/64, 768/64), 256, 0, stream>>>(W_e1, we1h, we1l, 2304, 768);
    wconv_t<<<dim3(768/64,  768/64), 256, 0, stream>>>(W_e2, we2h, we2l, 768, 768);
    wconv_t<<<dim3(1536/64, 768/64), 256, 0, stream>>>(W_m,  wmh,  wml,  1536, 768);
    wconv_t<<<dim3(768/64,  768/64), 256, 0, stream>>>(W_mg, wmgh, wmgl, 768, 768);
    wconv_t<<<dim3(768/64,  768/64), 256, 0, stream>>>(W_nh, wnhh, wnhl, 768, 768);
    wconv_t<<<dim3(768/64,  768/64), 256, 0, stream>>>(W_no, wnoh, wnol, 768, 768);
    for (int l = 0; l < 2; l++) {
        wconv_t<<<dim3(768/64, 2304/64), 256, 0, stream>>>(Wqkv + (size_t)l*768*2304, qkvh[l], qkvl[l], 768, 2304);
        wconv_t<<<dim3(768/64,  768/64), 256, 0, stream>>>(Wo_t + (size_t)l*768*768,  woh[l],  wol[l],  768, 768);
        wconv_t<<<dim3(768/64, 3072/64), 256, 0, stream>>>(Wf1  + (size_t)l*768*3072, wf1h[l], wf1l[l], 768, 3072);
        wconv_t<<<dim3(3072/64, 768/64), 256, 0, stream>>>(Wf2  + (size_t)l*3072*768, wf2h[l], wf2l[l], 3072, 768);
    }

    // ---- adaptive batch chunking over remaining ws ----
    const size_t avail = ws_size - wbytes;
    int CB = 4;
    {
        const int cands[5] = {64, 32, 16, 8, 4};
        for (int i = 0; i < 5; i++) {
            size_t R = (size_t)cands[i] * ROWS_PER_B;       // mult of 128
            size_t need = R * 21504 + (size_t)cands[i]*16*768*4 + R*4 + 8192;
            if (need <= avail) { CB = cands[i]; break; }
        }
    }
    const int R = CB * ROWS_PER_B;           // rows per chunk (mult of 128)
    const int nhuman = CB * FRAMES;
    const int nobjr  = CB * FRAMES * NOBJ;

    float* fbase = (float*)(wts + wo);
    float* Qbig = fbase;                                  // R x 2304 f32 (multi-use)
    float* X    = Qbig + (size_t)R * 2304;                // R x 768 f32
    float* Z    = X + (size_t)R * DMODEL;                 // R x 768 f32
    unsigned short* Xh = (unsigned short*)(Z + (size_t)R * DMODEL);
    unsigned short* Xl = Xh + (size_t)R * DMODEL;
    unsigned short* Yh = Xl + (size_t)R * DMODEL;
    unsigned short* Yl = Yh + (size_t)R * DMODEL;
    float* EWH = (float*)(Yl + (size_t)R * DMODEL);       // nhuman x 768
    float* WE  = EWH + (size_t)nhuman * DMODEL;           // R
    // aliases of Qbig:
    unsigned short* Q1h = (unsigned short*)Qbig;          // cat1 planes R x 2304
    unsigned short* Q1l = Q1h + (size_t)R * 2304;
    unsigned short* Q2h = (unsigned short*)Qbig;          // cat2 planes R x 1536
    unsigned short* Q2l = Q2h + (size_t)R * 1536;
    float* MV = Qbig;                                     // m_v, R x 768 f32

    auto G = [&](const unsigned short* Ah, const unsigned short* Al, int K,
                 const unsigned short* Bh, const unsigned short* Bl, int ldbv,
                 const float* bias, float* Cf, unsigned short* Chi,
                 unsigned short* Clo, int ldc, int M, int N, int act, int accum) {
        dim3 grid(N / 128, (M + 127) / 128);
        gemm_bf16s<<<grid, 256, 0, stream>>>(Ah, Al, Bh, Bl, ldbv, K, bias,
                                             Cf, Chi, Clo, ldc, M, act, accum);
    };

    for (int b0 = 0; b0 < BATCH; b0 += CB) {
        const int r0  = b0 * ROWS_PER_B;
        const int bf0 = b0 * FRAMES;

        // ---- edge MLP ----
        gather_cat1_k<<<R, 256, 0, stream>>>(hf, obj, edge, Q1h, Q1l, r0);
        G(Q1h, Q1l, 2304, we1h, we1l, 2304, b_e1, nullptr, Yh, Yl, 768, R, 768, 1, 0);
        G(Yh, Yl, 768, we2h, we2l, 768, b_e2, Z, nullptr, nullptr, 768, R, 768, 0, 0);
        ln_act_f32<<<R, 256, 0, stream>>>(Z, nullptr, g_e, be_e, X, Xh, Xl, 1);

        // ---- transformer (2 layers) ----
        for (int l = 0; l < NLAYERS; l++) {
            G(Xh, Xl, 768, qkvh[l], qkvl[l], 768, bqkv + (size_t)l * 2304,
              Qbig, nullptr, nullptr, 2304, R, 2304, 0, 0);
            attn_k<<<(R / 16) * NHEADS, 256, 0, stream>>>(Qbig, Yh, Yl);
            G(Yh, Yl, 768, woh[l], wol[l], 768, bo_t + (size_t)l * 768,
              Z, nullptr, nullptr, 768, R, 768, 0, 0);
            ln_act_f32<<<R, 256, 0, stream>>>(Z, X, g1 + l*DMODEL, bb1 + l*DMODEL, X, Xh, Xl, 0);
            for (int c = 0; c < 4; c++) {
                G(Xh, Xl, 768, wf1h[l] + (size_t)c*768*768, wf1l[l] + (size_t)c*768*768, 768,
                  bf1 + (size_t)l*FFD + c*768, nullptr, Yh, Yl, 768, R, 768, 1, 0);
                G(Yh, Yl, 768, wf2h[l] + (size_t)c*768, wf2l[l] + (size_t)c*768, 3072,
                  (c == 0 ? bf2 + (size_t)l*768 : nullptr), Z, nullptr, nullptr,
                  768, R, 768, 0, (c > 0) ? 1 : 0);
            }
            ln_act_f32<<<R, 256, 0, stream>>>(Z, X, g2 + l*DMODEL, bb2 + l*DMODEL, X, Xh, Xl, 0);
        }

        // ---- message passing epilogue ----
        wedge_k<<<R / 4, 256, 0, stream>>>(X, W_l, b_l, WE);
        gather_cat2_k<<<R, 256, 0, stream>>>(hf, obj, Xh, Xl, Q2h, Q2l, r0);
        G(Q2h, Q2l, 1536, wmh, wml, 1536, b_m, nullptr, Yh, Yl, 768, R, 768, 1, 0);
        G(Yh, Yl, 768, wmgh, wmgl, 768, b_mg, Z, nullptr, nullptr, 768, R, 768, 0, 0);
        ln_act_f32<<<R, 256, 0, stream>>>(Z, nullptr, g_mg, bb_mg, MV, nullptr, nullptr, 1);
        ewh_k<<<nhuman, 256, 0, stream>>>(MV, WE, EWH);
        buildA_k<<<nhuman + nobjr, 256, 0, stream>>>(EWH, MV, WE, hf, obj,
                                                     scale_h, scale_o, Xh, Xl, bf0, nhuman);
        G(Xh, Xl, 768, wnhh, wnhl, 768, b_nh, Z, nullptr, nullptr, 768, nhuman, 768, 0, 0);
        G(Xh + (size_t)nhuman*DMODEL, Xl + (size_t)nhuman*DMODEL, 768, wnoh, wnol, 768,
          b_no, Z + (size_t)nhuman*DMODEL, nullptr, nullptr, 768, nobjr, 768, 0, 0);
        ln_act_f32<<<nhuman, 256, 0, stream>>>(Z, nullptr, g_nh, bb_nh,
                                               out + (size_t)bf0 * DMODEL, nullptr, nullptr, 1);
        ln_act_f32<<<nobjr, 256, 0, stream>>>(Z + (size_t)nhuman*DMODEL, nullptr,
                                              g_no, bb_no,
                                              out + (size_t)NBF*DMODEL + (size_t)bf0*NOBJ*DMODEL,
                                              nullptr, nullptr, 1);
    }
}

// Round 6
// 4498.546 us; speedup vs baseline: 2.2235x; 1.4930x over previous
//
#include <hip/hip_runtime.h>
#include <math.h>

// ---------------------------------------------------------------------------
// GPNN cell: split-bf16 (hi+lo) MFMA GEMMs, 128x64 tiles, fused FF.
#define DMODEL 768
#define NHEADS 12
#define HEADD  64
#define NLAYERS 2
#define FFD    3072
#define BATCH  64
#define FRAMES 16
#define NOBJ   9
#define TWO_N  (2*NOBJ)                 // 18
#define ROWS_PER_B (TWO_N*FRAMES)       // 288 rows per batch
#define NBF    (BATCH*FRAMES)           // 1024

typedef float f32x4 __attribute__((ext_vector_type(4)));
typedef short s16x8 __attribute__((ext_vector_type(8)));
typedef unsigned short u16x8 __attribute__((ext_vector_type(8)));

__device__ __forceinline__ float gelu_f(float x) {
    return 0.5f * x * (1.0f + erff(x * 0.70710678118654752440f));
}
__device__ __forceinline__ unsigned short f2bf(float x) {
    unsigned u = __float_as_uint(x);
    unsigned r = (u + 0x7fffu + ((u >> 16) & 1u)) >> 16;
    return (unsigned short)r;
}
__device__ __forceinline__ float bf2f(unsigned short h) {
    return __uint_as_float(((unsigned)h) << 16);
}
__device__ __forceinline__ void store_hl(float v, unsigned short* ph, unsigned short* pl) {
    unsigned short h = f2bf(v);
    *ph = h;
    *pl = f2bf(v - bf2f(h));
}

// ---------------- weight transpose + hi/lo convert:  W[K][N] -> T[N][K] ----
__global__ __launch_bounds__(256) void wconv_t(
    const float* __restrict__ W, unsigned short* __restrict__ Th,
    unsigned short* __restrict__ Tl, int K, int N)
{
    __shared__ float s[64][65];
    const int k0 = blockIdx.x * 64, n0 = blockIdx.y * 64;
    const int tid = threadIdx.x;
    for (int i = tid; i < 4096; i += 256) {
        int r = i >> 6, c = i & 63;
        s[r][c] = W[(size_t)(k0 + r) * N + n0 + c];
    }
    __syncthreads();
    for (int i = tid; i < 4096; i += 256) {
        int n = i >> 6, k = i & 63;
        float x = s[k][n];
        unsigned short h = f2bf(x);
        size_t o = (size_t)(n0 + n) * K + k0 + k;
        Th[o] = h;
        Tl[o] = f2bf(x - bf2f(h));
    }
}

// ---------------- split-bf16 MFMA GEMM, tile 128x64, 4 waves (2x2) ---------
// C[M][N] = act(A @ W^T + bias); A row stride = K; B = WT[N][K] hi/lo.
// M need not be a multiple of 128 (guarded); A buffer must have
// ceil(M,128) valid-to-read rows. N % 64 == 0, K % 32 == 0.
__global__ __launch_bounds__(256) void gemm_bf16s(
    const unsigned short* __restrict__ Ah, const unsigned short* __restrict__ Al,
    const unsigned short* __restrict__ Bh, const unsigned short* __restrict__ Bl,
    int K, const float* __restrict__ bias,
    float* __restrict__ Cf, unsigned short* __restrict__ Chi,
    unsigned short* __restrict__ Clo,
    int ldc, int M, int act)
{
    __shared__ unsigned short lds[12288];   // Ah[128x32] Al Bh[64x32] Bl = 24 KB
    const int tid = threadIdx.x;
    const int wid = tid >> 6, l = tid & 63;
    const int row0 = blockIdx.y * 128;
    const int col0 = blockIdx.x * 64;

    // staging addresses (reg-staged, coalesced 16B/lane)
    const int srow = tid >> 2;              // 0..63
    const int scol = (tid & 3) << 3;        // 0,8,16,24
    const size_t ag = (size_t)(row0 + srow) * K + scol;
    const size_t bg = (size_t)(col0 + srow) * K + scol;
    const unsigned short* pAh0 = Ah + ag;
    const unsigned short* pAh1 = Ah + ag + (size_t)64 * K;
    const unsigned short* pAl0 = Al + ag;
    const unsigned short* pAl1 = Al + ag + (size_t)64 * K;
    const unsigned short* pBh  = Bh + bg;
    const unsigned short* pBl  = Bl + bg;
    const int wA0 = srow * 32 + scol;       // elems within plane
    const int wA1 = wA0 + 2048;

    // fragment read offsets
    const int wr = wid >> 1, wc = wid & 1;
    const int fr = l & 15, fs = l >> 4;
    int aoff[4], boff[2];
    #pragma unroll
    for (int m = 0; m < 4; m++) aoff[m] = (wr * 64 + m * 16 + fr) * 32 + fs * 8;
    #pragma unroll
    for (int n = 0; n < 2; n++) boff[n] = (wc * 32 + n * 16 + fr) * 32 + fs * 8;

    f32x4 acc[4][2];
    #pragma unroll
    for (int m = 0; m < 4; m++)
        #pragma unroll
        for (int n = 0; n < 2; n++) acc[m][n] = (f32x4){0.f, 0.f, 0.f, 0.f};

    u16x8 rah0 = *(const u16x8*)pAh0;
    u16x8 rah1 = *(const u16x8*)pAh1;
    u16x8 ral0 = *(const u16x8*)pAl0;
    u16x8 ral1 = *(const u16x8*)pAl1;
    u16x8 rbh  = *(const u16x8*)pBh;
    u16x8 rbl  = *(const u16x8*)pBl;

    for (int k0 = 0; k0 < K; k0 += 32) {
        __syncthreads();
        *(u16x8*)&lds[wA0]          = rah0;
        *(u16x8*)&lds[wA1]          = rah1;
        *(u16x8*)&lds[4096 + wA0]   = ral0;
        *(u16x8*)&lds[4096 + wA1]   = ral1;
        *(u16x8*)&lds[8192 + wA0]   = rbh;   // B rows 0..63 only (wA0<2048)
        *(u16x8*)&lds[10240 + wA0]  = rbl;
        __syncthreads();
        if (k0 + 32 < K) {                   // prefetch next K-tile into regs
            rah0 = *(const u16x8*)(pAh0 + k0 + 32);
            rah1 = *(const u16x8*)(pAh1 + k0 + 32);
            ral0 = *(const u16x8*)(pAl0 + k0 + 32);
            ral1 = *(const u16x8*)(pAl1 + k0 + 32);
            rbh  = *(const u16x8*)(pBh  + k0 + 32);
            rbl  = *(const u16x8*)(pBl  + k0 + 32);
        }
        s16x8 a_h[4], a_l[4], b_h[2], b_l[2];
        #pragma unroll
        for (int m = 0; m < 4; m++) {
            a_h[m] = *(const s16x8*)&lds[aoff[m]];
            a_l[m] = *(const s16x8*)&lds[4096 + aoff[m]];
        }
        #pragma unroll
        for (int n = 0; n < 2; n++) {
            b_h[n] = *(const s16x8*)&lds[8192 + boff[n]];
            b_l[n] = *(const s16x8*)&lds[10240 + boff[n]];
        }
        #pragma unroll
        for (int m = 0; m < 4; m++)
            #pragma unroll
            for (int n = 0; n < 2; n++) {
                acc[m][n] = __builtin_amdgcn_mfma_f32_16x16x32_bf16(a_h[m], b_h[n], acc[m][n], 0, 0, 0);
                acc[m][n] = __builtin_amdgcn_mfma_f32_16x16x32_bf16(a_l[m], b_h[n], acc[m][n], 0, 0, 0);
                acc[m][n] = __builtin_amdgcn_mfma_f32_16x16x32_bf16(a_h[m], b_l[n], acc[m][n], 0, 0, 0);
            }
    }

    // epilogue: C/D layout col = l&15, row = (l>>4)*4 + j  [m89-verified]
    #pragma unroll
    for (int n = 0; n < 2; n++) {
        int gcol = col0 + wc * 32 + n * 16 + fr;
        float bv = bias ? bias[gcol] : 0.f;
        #pragma unroll
        for (int m = 0; m < 4; m++) {
            int grow0 = row0 + wr * 64 + m * 16 + (fs << 2);
            #pragma unroll
            for (int j = 0; j < 4; j++) {
                int grow = grow0 + j;
                if (grow < M) {
                    float v = acc[m][n][j] + bv;
                    if (act) v = gelu_f(v);
                    size_t ci = (size_t)grow * ldc + gcol;
                    if (Cf) Cf[ci] = v;
                    if (Chi) store_hl(v, &Chi[ci], &Clo[ci]);
                }
            }
        }
    }
}

// ---------------- row LayerNorm (+residual, +gelu), fp32 + optional planes --
__global__ __launch_bounds__(256) void ln_act_f32(
    const float* __restrict__ in, const float* __restrict__ res,
    const float* __restrict__ gamma, const float* __restrict__ beta,
    float* __restrict__ outf, unsigned short* __restrict__ outh,
    unsigned short* __restrict__ outl, int do_gelu)
{
    const int row = blockIdx.x;
    const int tid = threadIdx.x;
    const size_t base = (size_t)row * DMODEL;
    float x0 = in[base + tid];
    float x1 = in[base + tid + 256];
    float x2 = in[base + tid + 512];
    if (res) {
        x0 += res[base + tid];
        x1 += res[base + tid + 256];
        x2 += res[base + tid + 512];
    }
    float s  = x0 + x1 + x2;
    float ss = x0 * x0 + x1 * x1 + x2 * x2;
    #pragma unroll
    for (int o = 32; o > 0; o >>= 1) {
        s  += __shfl_down(s,  o);
        ss += __shfl_down(ss, o);
    }
    __shared__ float sred[4], ssred[4], tot[2];
    const int lane = tid & 63, w = tid >> 6;
    if (lane == 0) { sred[w] = s; ssred[w] = ss; }
    __syncthreads();
    if (tid == 0) {
        tot[0] = sred[0] + sred[1] + sred[2] + sred[3];
        tot[1] = ssred[0] + ssred[1] + ssred[2] + ssred[3];
    }
    __syncthreads();
    const float mean = tot[0] * (1.0f / DMODEL);
    const float var  = tot[1] * (1.0f / DMODEL) - mean * mean;
    const float rstd = rsqrtf(var + 1e-5f);
    #pragma unroll
    for (int rep = 0; rep < 3; rep++) {
        int d = tid + rep * 256;
        float x = (rep == 0) ? x0 : (rep == 1) ? x1 : x2;
        float y = (x - mean) * rstd * gamma[d] + beta[d];
        if (do_gelu) y = gelu_f(y);
        if (outf) outf[base + d] = y;
        if (outh) store_hl(y, &outh[base + d], &outl[base + d]);
    }
}

// ---------------- attention: one block per (local sequence, head), T=16 ----
__global__ __launch_bounds__(256) void attn_k(
    const float* __restrict__ QKV,   // local R x 2304
    unsigned short* __restrict__ Oh, unsigned short* __restrict__ Ol)
{
    const int blk = blockIdx.x;
    const int h = blk % NHEADS;
    const int s = blk / NHEADS;
    __shared__ float q[16][HEADD], k[16][HEADD], v[16][HEADD], sc[16][17];
    const int tid = threadIdx.x;
    for (int idx = tid; idx < 16 * HEADD; idx += 256) {
        int t = idx >> 6, d = idx & 63;
        size_t base = (size_t)(s * 16 + t) * (3 * DMODEL) + h * HEADD + d;
        q[t][d] = QKV[base];
        k[t][d] = QKV[base + DMODEL];
        v[t][d] = QKV[base + 2 * DMODEL];
    }
    __syncthreads();
    {
        int qt = tid >> 4, kt = tid & 15;
        float a = 0.f;
        #pragma unroll
        for (int d = 0; d < HEADD; d++) a += q[qt][d] * k[kt][d];
        sc[qt][kt] = a * 0.125f;
    }
    __syncthreads();
    if (tid < 16) {
        float m = -1e30f;
        #pragma unroll
        for (int j = 0; j < 16; j++) m = fmaxf(m, sc[tid][j]);
        float sum = 0.f;
        #pragma unroll
        for (int j = 0; j < 16; j++) { float e = expf(sc[tid][j] - m); sc[tid][j] = e; sum += e; }
        float inv = 1.0f / sum;
        #pragma unroll
        for (int j = 0; j < 16; j++) sc[tid][j] *= inv;
    }
    __syncthreads();
    for (int idx = tid; idx < 16 * HEADD; idx += 256) {
        int qt = idx >> 6, d = idx & 63;
        float a = 0.f;
        #pragma unroll
        for (int kt = 0; kt < 16; kt++) a += sc[qt][kt] * v[kt][d];
        size_t o = (size_t)(s * 16 + qt) * DMODEL + h * HEADD + d;
        store_hl(a, &Oh[o], &Ol[o]);
    }
}

// ---------------- gathers (write hi/lo planes) ------------------------------
__global__ __launch_bounds__(256) void gather_cat1_k(
    const float* __restrict__ hf, const float* __restrict__ obj,
    const float* __restrict__ edge, unsigned short* __restrict__ Qh,
    unsigned short* __restrict__ Ql, int r0)
{
    const int rl = blockIdx.x;
    const int r = r0 + rl;
    const int f = r % FRAMES;
    const int sq = r / FRAMES;
    const int n2 = sq % TWO_N;
    const int b = sq / TWO_N;
    const int bf = b * FRAMES + f;
    const int n = (n2 < NOBJ) ? n2 : (n2 - NOBJ);
    const float* hfp = hf + (size_t)bf * DMODEL;
    const float* edp = edge + ((size_t)bf * NOBJ + n) * DMODEL;
    const float* obp = obj + ((size_t)bf * NOBJ + n) * DMODEL;
    const float* s0 = (n2 < NOBJ) ? hfp : obp;
    const float* s2 = (n2 < NOBJ) ? obp : hfp;
    const size_t ob = (size_t)rl * (3 * DMODEL);
    for (int i = threadIdx.x; i < 3 * DMODEL; i += 256) {
        float v = (i < DMODEL) ? s0[i]
                : (i < 2 * DMODEL) ? edp[i - DMODEL] : s2[i - 2 * DMODEL];
        store_hl(v, &Qh[ob + i], &Ql[ob + i]);
    }
}

__global__ __launch_bounds__(256) void gather_cat2_k(
    const float* __restrict__ hf, const float* __restrict__ obj,
    const unsigned short* __restrict__ Xh, const unsigned short* __restrict__ Xl,
    unsigned short* __restrict__ Qh, unsigned short* __restrict__ Ql, int r0)
{
    const int rl = blockIdx.x;
    const int r = r0 + rl;
    const int f = r % FRAMES;
    const int sq = r / FRAMES;
    const int n2 = sq % TWO_N;
    const int b = sq / TWO_N;
    const int bf = b * FRAMES + f;
    const float* s0 = (n2 < NOBJ)
        ? hf + (size_t)bf * DMODEL
        : obj + ((size_t)bf * NOBJ + (n2 - NOBJ)) * DMODEL;
    const size_t ob = (size_t)rl * (2 * DMODEL);
    const size_t xb = (size_t)rl * DMODEL;
    for (int i = threadIdx.x; i < 2 * DMODEL; i += 256) {
        if (i < DMODEL) {
            store_hl(s0[i], &Qh[ob + i], &Ql[ob + i]);
        } else {
            Qh[ob + i] = Xh[xb + i - DMODEL];
            Ql[ob + i] = Xl[xb + i - DMODEL];
        }
    }
}

// ---------------- weight_edge = sigmoid(X . W_l + b_l) ----------------------
__global__ __launch_bounds__(256) void wedge_k(
    const float* __restrict__ X, const float* __restrict__ Wl,
    const float* __restrict__ bl, float* __restrict__ WE)
{
    const int row = blockIdx.x * 4 + (threadIdx.x >> 6);
    const int lane = threadIdx.x & 63;
    const float* xp = X + (size_t)row * DMODEL;
    float a = 0.f;
    #pragma unroll
    for (int i = 0; i < DMODEL / 64; i++)
        a += xp[lane + i * 64] * Wl[lane + i * 64];
    #pragma unroll
    for (int o = 32; o > 0; o >>= 1) a += __shfl_down(a, o);
    if (lane == 0) WE[row] = 1.0f / (1.0f + expf(-(a + bl[0])));
}

// ---------------- ewh[bf_local,:] = sum_{n2<N} WE[rl] * m_v[rl,:] -----------
__global__ __launch_bounds__(256) void ewh_k(
    const float* __restrict__ MV, const float* __restrict__ WE,
    float* __restrict__ EWH)
{
    const int bfl = blockIdx.x;
    const int bl = bfl / FRAMES, f = bfl % FRAMES;
    const int tid = threadIdx.x;
    #pragma unroll
    for (int rep = 0; rep < 3; rep++) {
        int d = tid + rep * 256;
        float acc = 0.f;
        #pragma unroll
        for (int n2 = 0; n2 < NOBJ; n2++) {
            int rl = (bl * TWO_N + n2) * FRAMES + f;
            acc += WE[rl] * MV[(size_t)rl * DMODEL + d];
        }
        EWH[(size_t)bfl * DMODEL + d] = acc;
    }
}

// ---------------- A rows for final GEMMs: msg_norm(x,msg,s)+x → hi/lo -------
__global__ __launch_bounds__(256) void buildA_k(
    const float* __restrict__ EWH, const float* __restrict__ MV,
    const float* __restrict__ WE,  const float* __restrict__ hf,
    const float* __restrict__ obj, const float* __restrict__ scale_h,
    const float* __restrict__ scale_o, unsigned short* __restrict__ Ahp,
    unsigned short* __restrict__ Alp, int bf0, int nhuman)
{
    const int row = blockIdx.x;
    const int tid = threadIdx.x;
    const float* msgp; const float* xp; float wsc, sc;
    if (row < nhuman) {
        msgp = EWH + (size_t)row * DMODEL;
        xp   = hf  + (size_t)(bf0 + row) * DMODEL;
        wsc = 1.0f; sc = scale_h[0];
    } else {
        int idx = row - nhuman;
        int n   = idx % NOBJ;
        int bfl = idx / NOBJ;
        int bl = bfl / FRAMES, f = bfl % FRAMES;
        int rl = (bl * TWO_N + NOBJ + n) * FRAMES + f;
        msgp = MV + (size_t)rl * DMODEL;
        xp   = obj + ((size_t)(bf0 + bfl) * NOBJ + n) * DMODEL;
        wsc = WE[rl]; sc = scale_o[0];
    }
    float m0 = msgp[tid]       * wsc;
    float m1 = msgp[tid + 256] * wsc;
    float m2 = msgp[tid + 512] * wsc;
    float x0 = xp[tid], x1 = xp[tid + 256], x2 = xp[tid + 512];
    float sm = m0*m0 + m1*m1 + m2*m2;
    float sx = x0*x0 + x1*x1 + x2*x2;
    #pragma unroll
    for (int o = 32; o > 0; o >>= 1) {
        sm += __shfl_down(sm, o);
        sx += __shfl_down(sx, o);
    }
    __shared__ float smr[4], sxr[4], tot[2];
    const int lane = tid & 63, w = tid >> 6;
    if (lane == 0) { smr[w] = sm; sxr[w] = sx; }
    __syncthreads();
    if (tid == 0) {
        tot[0] = smr[0] + smr[1] + smr[2] + smr[3];
        tot[1] = sxr[0] + sxr[1] + sxr[2] + sxr[3];
    }
    __syncthreads();
    const float nm  = fmaxf(sqrtf(tot[0]), 1e-12f);
    const float fac = sqrtf(tot[1]) * sc / nm;
    const size_t ob = (size_t)row * DMODEL;
    store_hl(m0 * fac + x0, &Ahp[ob + tid],       &Alp[ob + tid]);
    store_hl(m1 * fac + x1, &Ahp[ob + tid + 256], &Alp[ob + tid + 256]);
    store_hl(m2 * fac + x2, &Ahp[ob + tid + 512], &Alp[ob + tid + 512]);
}

// ---------------------------------------------------------------------------
extern "C" void kernel_launch(void* const* d_in, const int* in_sizes, int n_in,
                              void* d_out, int out_size, void* d_ws, size_t ws_size,
                              hipStream_t stream)
{
    const float* hf   = (const float*)d_in[0];
    const float* obj  = (const float*)d_in[1];
    const float* edge = (const float*)d_in[2];
    const float* W_e1 = (const float*)d_in[3];
    const float* b_e1 = (const float*)d_in[4];
    const float* W_e2 = (const float*)d_in[5];
    const float* b_e2 = (const float*)d_in[6];
    const float* g_e  = (const float*)d_in[7];
    const float* be_e = (const float*)d_in[8];
    const float* W_m  = (const float*)d_in[9];
    const float* b_m  = (const float*)d_in[10];
    const float* W_mg = (const float*)d_in[11];
    const float* b_mg = (const float*)d_in[12];
    const float* g_mg = (const float*)d_in[13];
    const float* bb_mg= (const float*)d_in[14];
    const float* W_l  = (const float*)d_in[15];
    const float* b_l  = (const float*)d_in[16];
    const float* scale_h = (const float*)d_in[17];
    const float* scale_o = (const float*)d_in[18];
    const float* W_nh = (const float*)d_in[19];
    const float* b_nh = (const float*)d_in[20];
    const float* g_nh = (const float*)d_in[21];
    const float* bb_nh= (const float*)d_in[22];
    const float* W_no = (const float*)d_in[23];
    const float* b_no = (const float*)d_in[24];
    const float* g_no = (const float*)d_in[25];
    const float* bb_no= (const float*)d_in[26];
    const float* Wqkv = (const float*)d_in[27];
    const float* bqkv = (const float*)d_in[28];
    const float* Wo_t = (const float*)d_in[29];
    const float* bo_t = (const float*)d_in[30];
    const float* g1   = (const float*)d_in[31];
    const float* bb1  = (const float*)d_in[32];
    const float* Wf1  = (const float*)d_in[33];
    const float* bf1  = (const float*)d_in[34];
    const float* Wf2  = (const float*)d_in[35];
    const float* bf2  = (const float*)d_in[36];
    const float* g2   = (const float*)d_in[37];
    const float* bb2  = (const float*)d_in[38];

    float* out = (float*)d_out;
    unsigned short* wts = (unsigned short*)d_ws;

    // ---- transposed hi/lo weight planes in ws (converted every launch) ----
    size_t wo = 0;
    auto alloc2 = [&](size_t n, unsigned short** h, unsigned short** l) {
        *h = wts + wo; *l = wts + wo + n; wo += 2 * n;
    };
    unsigned short *we1h,*we1l,*we2h,*we2l,*wmh,*wml,*wmgh,*wmgl,*wnhh,*wnhl,*wnoh,*wnol;
    unsigned short *qkvh[2],*qkvl[2],*woh[2],*wol[2],*wf1h[2],*wf1l[2],*wf2h[2],*wf2l[2];
    alloc2((size_t)768*2304, &we1h, &we1l);
    alloc2((size_t)768*768,  &we2h, &we2l);
    alloc2((size_t)768*1536, &wmh,  &wml);
    alloc2((size_t)768*768,  &wmgh, &wmgl);
    alloc2((size_t)768*768,  &wnhh, &wnhl);
    alloc2((size_t)768*768,  &wnoh, &wnol);
    for (int l = 0; l < 2; l++) {
        alloc2((size_t)2304*768, &qkvh[l], &qkvl[l]);
        alloc2((size_t)768*768,  &woh[l],  &wol[l]);
        alloc2((size_t)3072*768, &wf1h[l], &wf1l[l]);
        alloc2((size_t)768*3072, &wf2h[l], &wf2l[l]);
    }
    const size_t wbytes = wo * sizeof(unsigned short);

    wconv_t<<<dim3(2304/64, 768/64), 256, 0, stream>>>(W_e1, we1h, we1l, 2304, 768);
    wconv_t<<<dim3(768/64,  768/64), 256, 0, stream>>>(W_e2, we2h, we2l, 768, 768);
    wconv_t<<<dim3(1536/64, 768/64), 256, 0, stream>>>(W_m,  wmh,  wml,  1536, 768);
    wconv_t<<<dim3(768/64,  768/64), 256, 0, stream>>>(W_mg, wmgh, wmgl, 768, 768);
    wconv_t<<<dim3(768/64,  768/64), 256, 0, stream>>>(W_nh, wnhh, wnhl, 768, 768);
    wconv_t<<<dim3(768/64,  768/64), 256, 0, stream>>>(W_no, wnoh, wnol, 768, 768);
    for (int l = 0; l < 2; l++) {
        wconv_t<<<dim3(768/64, 2304/64), 256, 0, stream>>>(Wqkv + (size_t)l*768*2304, qkvh[l], qkvl[l], 768, 2304);
        wconv_t<<<dim3(768/64,  768/64), 256, 0, stream>>>(Wo_t + (size_t)l*768*768,  woh[l],  wol[l],  768, 768);
        wconv_t<<<dim3(768/64, 3072/64), 256, 0, stream>>>(Wf1  + (size_t)l*768*3072, wf1h[l], wf1l[l], 768, 3072);
        wconv_t<<<dim3(3072/64, 768/64), 256, 0, stream>>>(Wf2  + (size_t)l*3072*768, wf2h[l], wf2l[l], 3072, 768);
    }

    // ---- adaptive batch chunking over remaining ws ----
    // need(CB) = R*27652 + CB*49152 bytes, R = 288*CB  (with Z/MV/Q1/Q2
    // overlaid into Qbig and Y planes sized R x 3072 for the fused FF).
    const size_t avail = ws_size - wbytes;
    int CB = 4;
    {
        const int cands[5] = {64, 32, 16, 8, 4};
        for (int i = 0; i < 5; i++) {
            size_t R = (size_t)cands[i] * ROWS_PER_B;
            size_t need = R * 27652 + (size_t)cands[i] * 49152 + 8192;
            if (need <= avail) { CB = cands[i]; break; }
        }
    }
    const int R = CB * ROWS_PER_B;           // rows per chunk
    const int nhuman = CB * FRAMES;
    const int nobjr  = CB * FRAMES * NOBJ;

    char* base = (char*)(wts + wo);
    float* Qbig = (float*)base;                            // R x 2304 f32
    float* X    = Qbig + (size_t)R * 2304;                 // R x 768 f32
    unsigned short* Xh = (unsigned short*)(X + (size_t)R * DMODEL);
    unsigned short* Xl = Xh + (size_t)R * DMODEL;
    unsigned short* Yh = Xl + (size_t)R * DMODEL;          // R x 3072 planes
    unsigned short* Yl = Yh + (size_t)R * FFD;
    float* EWH = (float*)(Yl + (size_t)R * FFD);           // nhuman x 768
    float* WE  = EWH + (size_t)nhuman * DMODEL;            // R
    // overlays within Qbig:
    float* Z  = Qbig;                                      // R x 768 f32
    float* MV = Qbig + (size_t)R * DMODEL;                 // R x 768 f32
    unsigned short* Q1h = (unsigned short*)Qbig;           // R x 2304 planes
    unsigned short* Q1l = Q1h + (size_t)R * 2304;
    unsigned short* Q2h = (unsigned short*)Qbig;           // R x 1536 planes
    unsigned short* Q2l = Q2h + (size_t)R * 1536;

    auto G = [&](const unsigned short* Ah, const unsigned short* Al, int K,
                 const unsigned short* Bh, const unsigned short* Bl,
                 const float* bias, float* Cf, unsigned short* Chi,
                 unsigned short* Clo, int ldc, int M, int N, int act) {
        dim3 grid(N / 64, (M + 127) / 128);
        gemm_bf16s<<<grid, 256, 0, stream>>>(Ah, Al, Bh, Bl, K, bias,
                                             Cf, Chi, Clo, ldc, M, act);
    };

    for (int b0 = 0; b0 < BATCH; b0 += CB) {
        const int r0  = b0 * ROWS_PER_B;
        const int bf0 = b0 * FRAMES;

        // ---- edge MLP ----
        gather_cat1_k<<<R, 256, 0, stream>>>(hf, obj, edge, Q1h, Q1l, r0);
        G(Q1h, Q1l, 2304, we1h, we1l, b_e1, nullptr, Yh, Yl, 768, R, 768, 1);
        G(Yh, Yl, 768, we2h, we2l, b_e2, Z, nullptr, nullptr, 768, R, 768, 0);
        ln_act_f32<<<R, 256, 0, stream>>>(Z, nullptr, g_e, be_e, X, Xh, Xl, 1);

        // ---- transformer (2 layers) ----
        for (int l = 0; l < NLAYERS; l++) {
            G(Xh, Xl, 768, qkvh[l], qkvl[l], bqkv + (size_t)l * 2304,
              Qbig, nullptr, nullptr, 2304, R, 2304, 0);
            attn_k<<<(R / 16) * NHEADS, 256, 0, stream>>>(Qbig, Yh, Yl);
            G(Yh, Yl, 768, woh[l], wol[l], bo_t + (size_t)l * 768,
              Z, nullptr, nullptr, 768, R, 768, 0);
            ln_act_f32<<<R, 256, 0, stream>>>(Z, X, g1 + l*DMODEL, bb1 + l*DMODEL, X, Xh, Xl, 0);
            // fused FF: one M x 3072 GEMM + one K=3072 GEMM
            G(Xh, Xl, 768, wf1h[l], wf1l[l], bf1 + (size_t)l * FFD,
              nullptr, Yh, Yl, FFD, R, FFD, 1);
            G(Yh, Yl, FFD, wf2h[l], wf2l[l], bf2 + (size_t)l * 768,
              Z, nullptr, nullptr, 768, R, 768, 0);
            ln_act_f32<<<R, 256, 0, stream>>>(Z, X, g2 + l*DMODEL, bb2 + l*DMODEL, X, Xh, Xl, 0);
        }

        // ---- message passing epilogue ----
        wedge_k<<<R / 4, 256, 0, stream>>>(X, W_l, b_l, WE);
        gather_cat2_k<<<R, 256, 0, stream>>>(hf, obj, Xh, Xl, Q2h, Q2l, r0);
        G(Q2h, Q2l, 1536, wmh, wml, b_m, nullptr, Yh, Yl, 768, R, 768, 1);
        G(Yh, Yl, 768, wmgh, wmgl, b_mg, Z, nullptr, nullptr, 768, R, 768, 0);
        ln_act_f32<<<R, 256, 0, stream>>>(Z, nullptr, g_mg, bb_mg, MV, nullptr, nullptr, 1);
        ewh_k<<<nhuman, 256, 0, stream>>>(MV, WE, EWH);
        buildA_k<<<nhuman + nobjr, 256, 0, stream>>>(EWH, MV, WE, hf, obj,
                                                     scale_h, scale_o, Xh, Xl, bf0, nhuman);
        G(Xh, Xl, 768, wnhh, wnhl, b_nh, Z, nullptr, nullptr, 768, nhuman, 768, 0);
        G(Xh + (size_t)nhuman*DMODEL, Xl + (size_t)nhuman*DMODEL, 768, wnoh, wnol,
          b_no, Z + (size_t)nhuman*DMODEL, nullptr, nullptr, 768, nobjr, 768, 0);
        ln_act_f32<<<nhuman, 256, 0, stream>>>(Z, nullptr, g_nh, bb_nh,
                                               out + (size_t)bf0 * DMODEL, nullptr, nullptr, 1);
        ln_act_f32<<<nobjr, 256, 0, stream>>>(Z + (size_t)nhuman*DMODEL, nullptr,
                                              g_no, bb_no,
                                              out + (size_t)NBF*DMODEL + (size_t)bf0*NOBJ*DMODEL,
                                              nullptr, nullptr, 1);
    }
}

// Round 9
// 4098.380 us; speedup vs baseline: 2.4406x; 1.0976x over previous
//
#include <hip/hip_runtime.h>
#include <math.h>

// ---------------------------------------------------------------------------
// GPNN cell: split-bf16 (hi+lo) MFMA GEMMs; all activations as hi/lo planes.
#define DMODEL 768
#define NHEADS 12
#define HEADD  64
#define NLAYERS 2
#define FFD    3072
#define BATCH  64
#define FRAMES 16
#define NOBJ   9
#define TWO_N  (2*NOBJ)                 // 18
#define ROWS_PER_B (TWO_N*FRAMES)       // 288 rows per batch
#define NBF    (BATCH*FRAMES)           // 1024

typedef float f32x4 __attribute__((ext_vector_type(4)));
typedef short s16x8 __attribute__((ext_vector_type(8)));
typedef unsigned short u16x8 __attribute__((ext_vector_type(8)));
typedef unsigned short u16;

__device__ __forceinline__ float gelu_f(float x) {
    return 0.5f * x * (1.0f + erff(x * 0.70710678118654752440f));
}
__device__ __forceinline__ u16 f2bf(float x) {
    unsigned u = __float_as_uint(x);
    unsigned r = (u + 0x7fffu + ((u >> 16) & 1u)) >> 16;
    return (u16)r;
}
__device__ __forceinline__ float bf2f(u16 h) {
    return __uint_as_float(((unsigned)h) << 16);
}
__device__ __forceinline__ void store_hl(float v, u16* ph, u16* pl) {
    u16 h = f2bf(v);
    *ph = h;
    *pl = f2bf(v - bf2f(h));
}

// ---------------- weight transpose + hi/lo convert:  W[K][N] -> T[N][K] ----
__global__ __launch_bounds__(256) void wconv_t(
    const float* __restrict__ W, u16* __restrict__ Th,
    u16* __restrict__ Tl, int K, int N)
{
    __shared__ float s[64][65];
    const int k0 = blockIdx.x * 64, n0 = blockIdx.y * 64;
    const int tid = threadIdx.x;
    for (int i = tid; i < 4096; i += 256) {
        int r = i >> 6, c = i & 63;
        s[r][c] = W[(size_t)(k0 + r) * N + n0 + c];
    }
    __syncthreads();
    for (int i = tid; i < 4096; i += 256) {
        int n = i >> 6, k = i & 63;
        float x = s[k][n];
        u16 h = f2bf(x);
        size_t o = (size_t)(n0 + n) * K + k0 + k;
        Th[o] = h;
        Tl[o] = f2bf(x - bf2f(h));
    }
}

// ---------------- split-bf16 MFMA GEMM, tile 128x64, 4 waves (2x2) ---------
// C[M][N] = [accum? C:0] + act(A @ W^T + bias); A row stride K; B = WT[N][K]
// with row stride == K (INVARIANT: all weight planes stored contiguously).
// N % 64 == 0, K % 32 == 0. A buffer must have ceil(M,128) readable rows.
__global__ __launch_bounds__(256) void gemm_bf16s(
    const u16* __restrict__ Ah, const u16* __restrict__ Al,
    const u16* __restrict__ Bh, const u16* __restrict__ Bl,
    int K, const float* __restrict__ bias,
    float* __restrict__ Cf, u16* __restrict__ Chi, u16* __restrict__ Clo,
    int ldc, int M, int act, int accum)
{
    __shared__ u16 lds[12288];   // Ah[128x32] Al Bh[64x32] Bl = 24 KB
    const int tid = threadIdx.x;
    const int wid = tid >> 6, l = tid & 63;

    // bijective XCD swizzle (all grids here are multiples of 8 blocks)
    int nwg = gridDim.x * gridDim.y;
    int bid = blockIdx.y * gridDim.x + blockIdx.x;
    if ((nwg & 7) == 0) bid = (bid & 7) * (nwg >> 3) + (bid >> 3);
    const int col0 = (bid % gridDim.x) * 64;
    const int row0 = (bid / gridDim.x) * 128;

    // staging addresses (reg-staged, coalesced 16B/lane)
    const int srow = tid >> 2;              // 0..63
    const int scol = (tid & 3) << 3;        // 0,8,16,24
    const size_t ag = (size_t)(row0 + srow) * K + scol;
    const size_t bg = (size_t)(col0 + srow) * K + scol;
    const u16* pAh0 = Ah + ag;
    const u16* pAh1 = Ah + ag + (size_t)64 * K;
    const u16* pAl0 = Al + ag;
    const u16* pAl1 = Al + ag + (size_t)64 * K;
    const u16* pBh  = Bh + bg;
    const u16* pBl  = Bl + bg;
    const int wA0 = srow * 32 + scol;       // elems within plane
    const int wA1 = wA0 + 2048;

    // fragment read offsets
    const int wr = wid >> 1, wc = wid & 1;
    const int fr = l & 15, fs = l >> 4;
    int aoff[4], boff[2];
    #pragma unroll
    for (int m = 0; m < 4; m++) aoff[m] = (wr * 64 + m * 16 + fr) * 32 + fs * 8;
    #pragma unroll
    for (int n = 0; n < 2; n++) boff[n] = (wc * 32 + n * 16 + fr) * 32 + fs * 8;

    f32x4 acc[4][2];
    #pragma unroll
    for (int m = 0; m < 4; m++)
        #pragma unroll
        for (int n = 0; n < 2; n++) acc[m][n] = (f32x4){0.f, 0.f, 0.f, 0.f};

    u16x8 rah0 = *(const u16x8*)pAh0;
    u16x8 rah1 = *(const u16x8*)pAh1;
    u16x8 ral0 = *(const u16x8*)pAl0;
    u16x8 ral1 = *(const u16x8*)pAl1;
    u16x8 rbh  = *(const u16x8*)pBh;
    u16x8 rbl  = *(const u16x8*)pBl;

    for (int k0 = 0; k0 < K; k0 += 32) {
        __syncthreads();
        *(u16x8*)&lds[wA0]          = rah0;
        *(u16x8*)&lds[wA1]          = rah1;
        *(u16x8*)&lds[4096 + wA0]   = ral0;
        *(u16x8*)&lds[4096 + wA1]   = ral1;
        *(u16x8*)&lds[8192 + wA0]   = rbh;   // B rows 0..63 only (wA0<2048)
        *(u16x8*)&lds[10240 + wA0]  = rbl;
        __syncthreads();
        if (k0 + 32 < K) {                   // prefetch next K-tile into regs
            rah0 = *(const u16x8*)(pAh0 + k0 + 32);
            rah1 = *(const u16x8*)(pAh1 + k0 + 32);
            ral0 = *(const u16x8*)(pAl0 + k0 + 32);
            ral1 = *(const u16x8*)(pAl1 + k0 + 32);
            rbh  = *(const u16x8*)(pBh  + k0 + 32);
            rbl  = *(const u16x8*)(pBl  + k0 + 32);
        }
        s16x8 a_h[4], a_l[4], b_h[2], b_l[2];
        #pragma unroll
        for (int m = 0; m < 4; m++) {
            a_h[m] = *(const s16x8*)&lds[aoff[m]];
            a_l[m] = *(const s16x8*)&lds[4096 + aoff[m]];
        }
        #pragma unroll
        for (int n = 0; n < 2; n++) {
            b_h[n] = *(const s16x8*)&lds[8192 + boff[n]];
            b_l[n] = *(const s16x8*)&lds[10240 + boff[n]];
        }
        #pragma unroll
        for (int m = 0; m < 4; m++)
            #pragma unroll
            for (int n = 0; n < 2; n++) {
                acc[m][n] = __builtin_amdgcn_mfma_f32_16x16x32_bf16(a_h[m], b_h[n], acc[m][n], 0, 0, 0);
                acc[m][n] = __builtin_amdgcn_mfma_f32_16x16x32_bf16(a_l[m], b_h[n], acc[m][n], 0, 0, 0);
                acc[m][n] = __builtin_amdgcn_mfma_f32_16x16x32_bf16(a_h[m], b_l[n], acc[m][n], 0, 0, 0);
            }
    }

    // epilogue: C/D layout col = l&15, row = (l>>4)*4 + j  [m89-verified]
    #pragma unroll
    for (int n = 0; n < 2; n++) {
        int gcol = col0 + wc * 32 + n * 16 + fr;
        float bv = bias ? bias[gcol] : 0.f;
        #pragma unroll
        for (int m = 0; m < 4; m++) {
            int grow0 = row0 + wr * 64 + m * 16 + (fs << 2);
            #pragma unroll
            for (int j = 0; j < 4; j++) {
                int grow = grow0 + j;
                if (grow < M) {
                    float v = acc[m][n][j] + bv;
                    if (act) v = gelu_f(v);
                    size_t ci = (size_t)grow * ldc + gcol;
                    if (accum) v += Cf[ci];
                    if (Cf) Cf[ci] = v;
                    if (Chi) store_hl(v, &Chi[ci], &Clo[ci]);
                }
            }
        }
    }
}

// ---------------- row LayerNorm; input f32, residual from planes -----------
__global__ __launch_bounds__(256) void ln_act(
    const float* __restrict__ in, const u16* __restrict__ resH,
    const u16* __restrict__ resL,
    const float* __restrict__ gamma, const float* __restrict__ beta,
    float* __restrict__ outF, u16* __restrict__ outH, u16* __restrict__ outL,
    int do_gelu)
{
    const int row = blockIdx.x;
    const int tid = threadIdx.x;
    const size_t base = (size_t)row * DMODEL;
    float x0 = in[base + tid];
    float x1 = in[base + tid + 256];
    float x2 = in[base + tid + 512];
    if (resH) {
        x0 += bf2f(resH[base + tid])       + bf2f(resL[base + tid]);
        x1 += bf2f(resH[base + tid + 256]) + bf2f(resL[base + tid + 256]);
        x2 += bf2f(resH[base + tid + 512]) + bf2f(resL[base + tid + 512]);
    }
    float s  = x0 + x1 + x2;
    float ss = x0 * x0 + x1 * x1 + x2 * x2;
    #pragma unroll
    for (int o = 32; o > 0; o >>= 1) {
        s  += __shfl_down(s,  o);
        ss += __shfl_down(ss, o);
    }
    __shared__ float sred[4], ssred[4], tot[2];
    const int lane = tid & 63, w = tid >> 6;
    if (lane == 0) { sred[w] = s; ssred[w] = ss; }
    __syncthreads();
    if (tid == 0) {
        tot[0] = sred[0] + sred[1] + sred[2] + sred[3];
        tot[1] = ssred[0] + ssred[1] + ssred[2] + ssred[3];
    }
    __syncthreads();
    const float mean = tot[0] * (1.0f / DMODEL);
    const float var  = tot[1] * (1.0f / DMODEL) - mean * mean;
    const float rstd = rsqrtf(var + 1e-5f);
    #pragma unroll
    for (int rep = 0; rep < 3; rep++) {
        int d = tid + rep * 256;
        float x = (rep == 0) ? x0 : (rep == 1) ? x1 : x2;
        float y = (x - mean) * rstd * gamma[d] + beta[d];
        if (do_gelu) y = gelu_f(y);
        if (outF) outF[base + d] = y;
        if (outH) store_hl(y, &outH[base + d], &outL[base + d]);
    }
}

// ---------------- attention: one block per (local sequence, head), T=16 ----
// QKV given as hi/lo planes, row stride 2304.
__global__ __launch_bounds__(256) void attn_k(
    const u16* __restrict__ Qh, const u16* __restrict__ Ql,
    u16* __restrict__ Oh, u16* __restrict__ Ol)
{
    const int blk = blockIdx.x;
    const int h = blk % NHEADS;
    const int s = blk / NHEADS;
    __shared__ float q[16][HEADD], k[16][HEADD], v[16][HEADD], sc[16][17];
    const int tid = threadIdx.x;
    for (int idx = tid; idx < 16 * HEADD; idx += 256) {
        int t = idx >> 6, d = idx & 63;
        size_t base = (size_t)(s * 16 + t) * (3 * DMODEL) + h * HEADD + d;
        q[t][d] = bf2f(Qh[base])              + bf2f(Ql[base]);
        k[t][d] = bf2f(Qh[base + DMODEL])     + bf2f(Ql[base + DMODEL]);
        v[t][d] = bf2f(Qh[base + 2 * DMODEL]) + bf2f(Ql[base + 2 * DMODEL]);
    }
    __syncthreads();
    {
        int qt = tid >> 4, kt = tid & 15;
        float a = 0.f;
        #pragma unroll
        for (int d = 0; d < HEADD; d++) a += q[qt][d] * k[kt][d];
        sc[qt][kt] = a * 0.125f;
    }
    __syncthreads();
    if (tid < 16) {
        float m = -1e30f;
        #pragma unroll
        for (int j = 0; j < 16; j++) m = fmaxf(m, sc[tid][j]);
        float sum = 0.f;
        #pragma unroll
        for (int j = 0; j < 16; j++) { float e = expf(sc[tid][j] - m); sc[tid][j] = e; sum += e; }
        float inv = 1.0f / sum;
        #pragma unroll
        for (int j = 0; j < 16; j++) sc[tid][j] *= inv;
    }
    __syncthreads();
    for (int idx = tid; idx < 16 * HEADD; idx += 256) {
        int qt = idx >> 6, d = idx & 63;
        float a = 0.f;
        #pragma unroll
        for (int kt = 0; kt < 16; kt++) a += sc[qt][kt] * v[kt][d];
        size_t o = (size_t)(s * 16 + qt) * DMODEL + h * HEADD + d;
        store_hl(a, &Oh[o], &Ol[o]);
    }
}

// ---------------- gathers (write hi/lo planes) ------------------------------
__global__ __launch_bounds__(256) void gather_cat1_k(
    const float* __restrict__ hf, const float* __restrict__ obj,
    const float* __restrict__ edge, u16* __restrict__ Qh,
    u16* __restrict__ Ql, int r0)
{
    const int rl = blockIdx.x;
    const int r = r0 + rl;
    const int f = r % FRAMES;
    const int sq = r / FRAMES;
    const int n2 = sq % TWO_N;
    const int b = sq / TWO_N;
    const int bf = b * FRAMES + f;
    const int n = (n2 < NOBJ) ? n2 : (n2 - NOBJ);
    const float* hfp = hf + (size_t)bf * DMODEL;
    const float* edp = edge + ((size_t)bf * NOBJ + n) * DMODEL;
    const float* obp = obj + ((size_t)bf * NOBJ + n) * DMODEL;
    const float* s0 = (n2 < NOBJ) ? hfp : obp;
    const float* s2 = (n2 < NOBJ) ? obp : hfp;
    const size_t ob = (size_t)rl * (3 * DMODEL);
    for (int i = threadIdx.x; i < 3 * DMODEL; i += 256) {
        float v = (i < DMODEL) ? s0[i]
                : (i < 2 * DMODEL) ? edp[i - DMODEL] : s2[i - 2 * DMODEL];
        store_hl(v, &Qh[ob + i], &Ql[ob + i]);
    }
}

__global__ __launch_bounds__(256) void gather_cat2_k(
    const float* __restrict__ hf, const float* __restrict__ obj,
    const u16* __restrict__ Xh, const u16* __restrict__ Xl,
    u16* __restrict__ Qh, u16* __restrict__ Ql, int r0)
{
    const int rl = blockIdx.x;
    const int r = r0 + rl;
    const int f = r % FRAMES;
    const int sq = r / FRAMES;
    const int n2 = sq % TWO_N;
    const int b = sq / TWO_N;
    const int bf = b * FRAMES + f;
    const float* s0 = (n2 < NOBJ)
        ? hf + (size_t)bf * DMODEL
        : obj + ((size_t)bf * NOBJ + (n2 - NOBJ)) * DMODEL;
    const size_t ob = (size_t)rl * (2 * DMODEL);
    const size_t xb = (size_t)rl * DMODEL;
    for (int i = threadIdx.x; i < 2 * DMODEL; i += 256) {
        if (i < DMODEL) {
            store_hl(s0[i], &Qh[ob + i], &Ql[ob + i]);
        } else {
            Qh[ob + i] = Xh[xb + i - DMODEL];
            Ql[ob + i] = Xl[xb + i - DMODEL];
        }
    }
}

// ---------------- weight_edge = sigmoid(X . W_l + b_l), X from planes ------
__global__ __launch_bounds__(256) void wedge_k(
    const u16* __restrict__ Xh, const u16* __restrict__ Xl,
    const float* __restrict__ Wl, const float* __restrict__ bl,
    float* __restrict__ WE)
{
    const int row = blockIdx.x * 4 + (threadIdx.x >> 6);
    const int lane = threadIdx.x & 63;
    const size_t base = (size_t)row * DMODEL;
    float a = 0.f;
    #pragma unroll
    for (int i = 0; i < DMODEL / 64; i++) {
        int d = lane + i * 64;
        a += (bf2f(Xh[base + d]) + bf2f(Xl[base + d])) * Wl[d];
    }
    #pragma unroll
    for (int o = 32; o > 0; o >>= 1) a += __shfl_down(a, o);
    if (lane == 0) WE[row] = 1.0f / (1.0f + expf(-(a + bl[0])));
}

// ---------------- ewh[bf_local,:] = sum_{n2<N} WE[rl] * m_v[rl,:] -----------
__global__ __launch_bounds__(256) void ewh_k(
    const float* __restrict__ MV, const float* __restrict__ WE,
    float* __restrict__ EWH)
{
    const int bfl = blockIdx.x;
    const int bl = bfl / FRAMES, f = bfl % FRAMES;
    const int tid = threadIdx.x;
    #pragma unroll
    for (int rep = 0; rep < 3; rep++) {
        int d = tid + rep * 256;
        float acc = 0.f;
        #pragma unroll
        for (int n2 = 0; n2 < NOBJ; n2++) {
            int rl = (bl * TWO_N + n2) * FRAMES + f;
            acc += WE[rl] * MV[(size_t)rl * DMODEL + d];
        }
        EWH[(size_t)bfl * DMODEL + d] = acc;
    }
}

// ---------------- A rows for final GEMMs: msg_norm(x,msg,s)+x → hi/lo -------
__global__ __launch_bounds__(256) void buildA_k(
    const float* __restrict__ EWH, const float* __restrict__ MV,
    const float* __restrict__ WE,  const float* __restrict__ hf,
    const float* __restrict__ obj, const float* __restrict__ scale_h,
    const float* __restrict__ scale_o, u16* __restrict__ Ahp,
    u16* __restrict__ Alp, int bf0, int nhuman)
{
    const int row = blockIdx.x;
    const int tid = threadIdx.x;
    const float* msgp; const float* xp; float wsc, sc;
    if (row < nhuman) {
        msgp = EWH + (size_t)row * DMODEL;
        xp   = hf  + (size_t)(bf0 + row) * DMODEL;
        wsc = 1.0f; sc = scale_h[0];
    } else {
        int idx = row - nhuman;
        int n   = idx % NOBJ;
        int bfl = idx / NOBJ;
        int bl = bfl / FRAMES, f = bfl % FRAMES;
        int rl = (bl * TWO_N + NOBJ + n) * FRAMES + f;
        msgp = MV + (size_t)rl * DMODEL;
        xp   = obj + ((size_t)(bf0 + bfl) * NOBJ + n) * DMODEL;
        wsc = WE[rl]; sc = scale_o[0];
    }
    float m0 = msgp[tid]       * wsc;
    float m1 = msgp[tid + 256] * wsc;
    float m2 = msgp[tid + 512] * wsc;
    float x0 = xp[tid], x1 = xp[tid + 256], x2 = xp[tid + 512];
    float sm = m0*m0 + m1*m1 + m2*m2;
    float sx = x0*x0 + x1*x1 + x2*x2;
    #pragma unroll
    for (int o = 32; o > 0; o >>= 1) {
        sm += __shfl_down(sm, o);
        sx += __shfl_down(sx, o);
    }
    __shared__ float smr[4], sxr[4], tot[2];
    const int lane = tid & 63, w = tid >> 6;
    if (lane == 0) { smr[w] = sm; sxr[w] = sx; }
    __syncthreads();
    if (tid == 0) {
        tot[0] = smr[0] + smr[1] + smr[2] + smr[3];
        tot[1] = sxr[0] + sxr[1] + sxr[2] + sxr[3];
    }
    __syncthreads();
    const float nm  = fmaxf(sqrtf(tot[0]), 1e-12f);
    const float fac = sqrtf(tot[1]) * sc / nm;
    const size_t ob = (size_t)row * DMODEL;
    store_hl(m0 * fac + x0, &Ahp[ob + tid],       &Alp[ob + tid]);
    store_hl(m1 * fac + x1, &Ahp[ob + tid + 256], &Alp[ob + tid + 256]);
    store_hl(m2 * fac + x2, &Ahp[ob + tid + 512], &Alp[ob + tid + 512]);
}

// ---------------------------------------------------------------------------
extern "C" void kernel_launch(void* const* d_in, const int* in_sizes, int n_in,
                              void* d_out, int out_size, void* d_ws, size_t ws_size,
                              hipStream_t stream)
{
    const float* hf   = (const float*)d_in[0];
    const float* obj  = (const float*)d_in[1];
    const float* edge = (const float*)d_in[2];
    const float* W_e1 = (const float*)d_in[3];
    const float* b_e1 = (const float*)d_in[4];
    const float* W_e2 = (const float*)d_in[5];
    const float* b_e2 = (const float*)d_in[6];
    const float* g_e  = (const float*)d_in[7];
    const float* be_e = (const float*)d_in[8];
    const float* W_m  = (const float*)d_in[9];
    const float* b_m  = (const float*)d_in[10];
    const float* W_mg = (const float*)d_in[11];
    const float* b_mg = (const float*)d_in[12];
    const float* g_mg = (const float*)d_in[13];
    const float* bb_mg= (const float*)d_in[14];
    const float* W_l  = (const float*)d_in[15];
    const float* b_l  = (const float*)d_in[16];
    const float* scale_h = (const float*)d_in[17];
    const float* scale_o = (const float*)d_in[18];
    const float* W_nh = (const float*)d_in[19];
    const float* b_nh = (const float*)d_in[20];
    const float* g_nh = (const float*)d_in[21];
    const float* bb_nh= (const float*)d_in[22];
    const float* W_no = (const float*)d_in[23];
    const float* b_no = (const float*)d_in[24];
    const float* g_no = (const float*)d_in[25];
    const float* bb_no= (const float*)d_in[26];
    const float* Wqkv = (const float*)d_in[27];
    const float* bqkv = (const float*)d_in[28];
    const float* Wo_t = (const float*)d_in[29];
    const float* bo_t = (const float*)d_in[30];
    const float* g1   = (const float*)d_in[31];
    const float* bb1  = (const float*)d_in[32];
    const float* Wf1  = (const float*)d_in[33];
    const float* bf1  = (const float*)d_in[34];
    const float* Wf2  = (const float*)d_in[35];
    const float* bf2  = (const float*)d_in[36];
    const float* g2   = (const float*)d_in[37];
    const float* bb2  = (const float*)d_in[38];

    float* out = (float*)d_out;
    u16* wts = (u16*)d_ws;

    // ---- transposed hi/lo weight planes (converted every launch) ----
    size_t wo = 0;
    auto alloc2 = [&](size_t n, u16** h, u16** l) {
        *h = wts + wo; *l = wts + wo + n; wo += 2 * n;
    };
    u16 *we1h,*we1l,*we2h,*we2l,*wmh,*wml,*wmgh,*wmgl,*wnhh,*wnhl,*wnoh,*wnol;
    u16 *qkvh[2],*qkvl[2],*woh[2],*wol[2],*wf1h[2],*wf1l[2],*wf2h[2],*wf2l[2];
    alloc2((size_t)768*2304, &we1h, &we1l);
    alloc2((size_t)768*768,  &we2h, &we2l);
    alloc2((size_t)768*1536, &wmh,  &wml);
    alloc2((size_t)768*768,  &wmgh, &wmgl);
    alloc2((size_t)768*768,  &wnhh, &wnhl);
    alloc2((size_t)768*768,  &wnoh, &wnol);
    for (int l = 0; l < 2; l++) {
        alloc2((size_t)2304*768, &qkvh[l], &qkvl[l]);
        alloc2((size_t)768*768,  &woh[l],  &wol[l]);
        alloc2((size_t)3072*768, &wf1h[l], &wf1l[l]);
        alloc2((size_t)768*3072, &wf2h[l], &wf2l[l]);   // two [768][1536] halves
    }
    const size_t wbytes = wo * sizeof(u16);

    wconv_t<<<dim3(2304/64, 768/64), 256, 0, stream>>>(W_e1, we1h, we1l, 2304, 768);
    wconv_t<<<dim3(768/64,  768/64), 256, 0, stream>>>(W_e2, we2h, we2l, 768, 768);
    wconv_t<<<dim3(1536/64, 768/64), 256, 0, stream>>>(W_m,  wmh,  wml,  1536, 768);
    wconv_t<<<dim3(768/64,  768/64), 256, 0, stream>>>(W_mg, wmgh, wmgl, 768, 768);
    wconv_t<<<dim3(768/64,  768/64), 256, 0, stream>>>(W_nh, wnhh, wnhl, 768, 768);
    wconv_t<<<dim3(768/64,  768/64), 256, 0, stream>>>(W_no, wnoh, wnol, 768, 768);
    for (int l = 0; l < 2; l++) {
        wconv_t<<<dim3(768/64, 2304/64), 256, 0, stream>>>(Wqkv + (size_t)l*768*2304, qkvh[l], qkvl[l], 768, 2304);
        wconv_t<<<dim3(768/64,  768/64), 256, 0, stream>>>(Wo_t + (size_t)l*768*768,  woh[l],  wol[l],  768, 768);
        wconv_t<<<dim3(768/64, 3072/64), 256, 0, stream>>>(Wf1  + (size_t)l*768*3072, wf1h[l], wf1l[l], 768, 3072);
        // wf2: per-half convert so each half is T[768][1536] with row stride 1536
        for (int c = 0; c < 2; c++) {
            wconv_t<<<dim3(1536/64, 768/64), 256, 0, stream>>>(
                Wf2 + (size_t)l*3072*768 + (size_t)c*1536*768,
                wf2h[l] + (size_t)c*768*1536, wf2l[l] + (size_t)c*768*1536,
                1536, 768);
        }
    }

    // ---- adaptive batch chunking over remaining ws ----
    // per-row bytes: X planes 3072 + Y planes (R x 1536 x 2 x 2B) 6144
    //              + QKVZ region 9216 + WE 4  => 18436; plus EWH CB*49152.
    const size_t avail = ws_size - wbytes;
    int CB = 4;
    {
        const int cands[5] = {64, 32, 16, 8, 4};
        for (int i = 0; i < 5; i++) {
            size_t R = (size_t)cands[i] * ROWS_PER_B;
            size_t need = R * 18436 + (size_t)cands[i] * 49152 + 65536;
            if (need <= avail) { CB = cands[i]; break; }
        }
    }
    const int R = CB * ROWS_PER_B;           // rows per chunk
    const int nhuman = CB * FRAMES;
    const int nobjr  = CB * FRAMES * NOBJ;

    u16* Xh = wts + wo;                     // R x 768 planes (residual / GEMM A)
    u16* Xl = Xh + (size_t)R * DMODEL;
    u16* Yh = Xl + (size_t)R * DMODEL;      // R x 1536 planes (multi-use)
    u16* Yl = Yh + (size_t)R * 1536;
    char* QKVZ = (char*)(Yl + (size_t)R * 1536);   // R x 9216 bytes region
    float* EWH = (float*)(QKVZ + (size_t)R * 9216);
    float* WE  = EWH + (size_t)nhuman * DMODEL;
    // overlays:
    u16* Qbh = (u16*)QKVZ;                  // qkv out / cat1 planes (R x 2304)
    u16* Qbl = Qbh + (size_t)R * 2304;
    u16* Q2h = (u16*)QKVZ;                  // cat2 planes (R x 1536)
    u16* Q2l = Q2h + (size_t)R * 1536;
    float* Z  = (float*)QKVZ;               // pre-LN f32 (R x 768)
    float* MV = (float*)Yh;                 // m_v f32 (R x 768), overlays Y

    auto G = [&](const u16* Ah, const u16* Al, int K,
                 const u16* Bh, const u16* Bl, const float* bias,
                 float* Cf, u16* Chi, u16* Clo, int ldc, int M, int N,
                 int act, int accum) {
        dim3 grid(N / 64, (M + 127) / 128);
        gemm_bf16s<<<grid, 256, 0, stream>>>(Ah, Al, Bh, Bl, K, bias,
                                             Cf, Chi, Clo, ldc, M, act, accum);
    };

    for (int b0 = 0; b0 < BATCH; b0 += CB) {
        const int r0  = b0 * ROWS_PER_B;
        const int bf0 = b0 * FRAMES;

        // ---- edge MLP ----
        gather_cat1_k<<<R, 256, 0, stream>>>(hf, obj, edge, Qbh, Qbl, r0);
        G(Qbh, Qbl, 2304, we1h, we1l, b_e1, nullptr, Yh, Yl, 768, R, 768, 1, 0);
        G(Yh, Yl, 768, we2h, we2l, b_e2, Z, nullptr, nullptr, 768, R, 768, 0, 0);
        ln_act<<<R, 256, 0, stream>>>(Z, nullptr, nullptr, g_e, be_e,
                                      nullptr, Xh, Xl, 1);

        // ---- transformer (2 layers) ----
        for (int l = 0; l < NLAYERS; l++) {
            G(Xh, Xl, 768, qkvh[l], qkvl[l], bqkv + (size_t)l * 2304,
              nullptr, Qbh, Qbl, 2304, R, 2304, 0, 0);
            attn_k<<<(R / 16) * NHEADS, 256, 0, stream>>>(Qbh, Qbl, Yh, Yl);
            G(Yh, Yl, 768, woh[l], wol[l], bo_t + (size_t)l * 768,
              Z, nullptr, nullptr, 768, R, 768, 0, 0);
            ln_act<<<R, 256, 0, stream>>>(Z, Xh, Xl, g1 + l*DMODEL, bb1 + l*DMODEL,
                                          nullptr, Xh, Xl, 0);
            // FF in two hidden halves of 1536 (wf2 halves each row-stride 1536)
            for (int c = 0; c < 2; c++) {
                G(Xh, Xl, 768, wf1h[l] + (size_t)c*1536*768, wf1l[l] + (size_t)c*1536*768,
                  bf1 + (size_t)l*FFD + c*1536, nullptr, Yh, Yl, 1536, R, 1536, 1, 0);
                G(Yh, Yl, 1536, wf2h[l] + (size_t)c*768*1536, wf2l[l] + (size_t)c*768*1536,
                  (c == 0 ? bf2 + (size_t)l*768 : nullptr), Z, nullptr, nullptr,
                  768, R, 768, 0, (c > 0) ? 1 : 0);
            }
            ln_act<<<R, 256, 0, stream>>>(Z, Xh, Xl, g2 + l*DMODEL, bb2 + l*DMODEL,
                                          nullptr, Xh, Xl, 0);
        }

        // ---- message passing epilogue ----
        wedge_k<<<R / 4, 256, 0, stream>>>(Xh, Xl, W_l, b_l, WE);
        gather_cat2_k<<<R, 256, 0, stream>>>(hf, obj, Xh, Xl, Q2h, Q2l, r0);
        G(Q2h, Q2l, 1536, wmh, wml, b_m, nullptr, Yh, Yl, 768, R, 768, 1, 0);
        G(Yh, Yl, 768, wmgh, wmgl, b_mg, Z, nullptr, nullptr, 768, R, 768, 0, 0);
        ln_act<<<R, 256, 0, stream>>>(Z, nullptr, nullptr, g_mg, bb_mg,
                                      MV, nullptr, nullptr, 1);
        ewh_k<<<nhuman, 256, 0, stream>>>(MV, WE, EWH);
        buildA_k<<<nhuman + nobjr, 256, 0, stream>>>(EWH, MV, WE, hf, obj,
                                                     scale_h, scale_o, Xh, Xl, bf0, nhuman);
        G(Xh, Xl, 768, wnhh, wnhl, b_nh, Z, nullptr, nullptr, 768, nhuman, 768, 0, 0);
        G(Xh + (size_t)nhuman*DMODEL, Xl + (size_t)nhuman*DMODEL, 768, wnoh, wnol,
          b_no, Z + (size_t)nhuman*DMODEL, nullptr, nullptr, 768, nobjr, 768, 0, 0);
        ln_act<<<nhuman, 256, 0, stream>>>(Z, nullptr, nullptr, g_nh, bb_nh,
                                           out + (size_t)bf0 * DMODEL, nullptr, nullptr, 1);
        ln_act<<<nobjr, 256, 0, stream>>>(Z + (size_t)nhuman*DMODEL, nullptr, nullptr,
                                          g_no, bb_no,
                                          out + (size_t)NBF*DMODEL + (size_t)bf0*NOBJ*DMODEL,
                                          nullptr, nullptr, 1);
    }
}